// Round 1
// baseline (456.867 us; speedup 1.0000x reference)
//
#include <hip/hip_runtime.h>

typedef __attribute__((ext_vector_type(8))) short short8;
typedef __attribute__((ext_vector_type(4))) float f32x4;
typedef unsigned short u16;
typedef unsigned int u32;

#define NB 4
#define CH 128
#define INTER2 64
#define HW2 9216
#define NN 4608

__device__ __forceinline__ u16 f2bf(float f) {
  u32 u = __float_as_uint(f);
  u += 0x7fffu + ((u >> 16) & 1u);
  return (u16)(u >> 16);
}
__device__ __forceinline__ float bf2f(u16 h) { return __uint_as_float(((u32)h) << 16); }
__device__ __forceinline__ u32 packbf(float a, float b) {
  return (u32)f2bf(a) | ((u32)f2bf(b) << 16);
}

// ---------------- K0: w_mask f32 -> bf16 ----------------
__global__ void k_wcvt(const float* __restrict__ wm, u16* __restrict__ wmb) {
  int i = blockIdx.x * 256 + threadIdx.x;
  if (i < CH * INTER2) wmb[i] = f2bf(wm[i]);
}

// ---------------- K1a: theta = w_theta @ x1, stored transposed Tt[b][n][cc] ----------------
// Tt[n][cc] = theta[cc>>1][(cc&1)*4608 + n]  (== column n of the [128,4608] view, k-contiguous)
__global__ __launch_bounds__(256) void k_theta(const float* __restrict__ x1,
                                               const float* __restrict__ wt,
                                               u16* __restrict__ Tt) {
  __shared__ float wT[CH][INTER2];  // wT[c][i]
  const int tid = threadIdx.x;
  for (int idx = tid; idx < INTER2 * CH; idx += 256) {
    int i = idx >> 7, c = idx & 127;
    wT[c][i] = wt[idx];
  }
  __syncthreads();
  const int nl = tid & 63, grp = tid >> 6;
  const int b = blockIdx.y;
  const int n = blockIdx.x * 64 + nl;
  const float* X = x1 + (size_t)b * CH * HW2;
  const int i0 = grp * 16;
  float acc[32];
#pragma unroll
  for (int q = 0; q < 32; q++) acc[q] = 0.f;
  for (int c = 0; c < CH; c++) {
    float xa = X[c * HW2 + n];
    float xb = X[c * HW2 + NN + n];
#pragma unroll
    for (int ii = 0; ii < 16; ii++) {
      float wv = wT[c][i0 + ii];
      acc[2 * ii] += wv * xa;
      acc[2 * ii + 1] += wv * xb;
    }
  }
  uint4* dst = (uint4*)(Tt + ((size_t)b * NN + n) * CH + 2 * i0);
#pragma unroll
  for (int q = 0; q < 4; q++) {
    uint4 v;
    v.x = packbf(acc[8 * q + 0], acc[8 * q + 1]);
    v.y = packbf(acc[8 * q + 2], acc[8 * q + 3]);
    v.z = packbf(acc[8 * q + 4], acc[8 * q + 5]);
    v.w = packbf(acc[8 * q + 6], acc[8 * q + 7]);
    dst[q] = v;
  }
}

// ---------------- K1bc: phi (transposed Pt[b][m][cc]) and g (natural Gv[b][cc][m]) from x2 ----------------
__global__ __launch_bounds__(256) void k_phi_g(const float* __restrict__ x2,
                                               const float* __restrict__ wp,
                                               const float* __restrict__ wg,
                                               u16* __restrict__ Pt,
                                               u16* __restrict__ Gv) {
  __shared__ float wpT[CH][INTER2];
  __shared__ float wgT[CH][INTER2];
  const int tid = threadIdx.x;
  for (int idx = tid; idx < INTER2 * CH; idx += 256) {
    int i = idx >> 7, c = idx & 127;
    wpT[c][i] = wp[idx];
    wgT[c][i] = wg[idx];
  }
  __syncthreads();
  const int ml = tid & 63, grp = tid >> 6;
  const int b = blockIdx.y;
  const int m = blockIdx.x * 64 + ml;
  const float* X = x2 + (size_t)b * CH * HW2;
  const int i0 = grp * 16;
  float accp[32], accg[32];
#pragma unroll
  for (int q = 0; q < 32; q++) { accp[q] = 0.f; accg[q] = 0.f; }
  for (int c = 0; c < CH; c++) {
    float xa = X[c * HW2 + m];
    float xb = X[c * HW2 + NN + m];
#pragma unroll
    for (int ii = 0; ii < 16; ii++) {
      float wv = wpT[c][i0 + ii];
      accp[2 * ii] += wv * xa;
      accp[2 * ii + 1] += wv * xb;
      float gv = wgT[c][i0 + ii];
      accg[2 * ii] += gv * xa;
      accg[2 * ii + 1] += gv * xb;
    }
  }
  uint4* dst = (uint4*)(Pt + ((size_t)b * NN + m) * CH + 2 * i0);
#pragma unroll
  for (int q = 0; q < 4; q++) {
    uint4 v;
    v.x = packbf(accp[8 * q + 0], accp[8 * q + 1]);
    v.y = packbf(accp[8 * q + 2], accp[8 * q + 3]);
    v.z = packbf(accp[8 * q + 4], accp[8 * q + 5]);
    v.w = packbf(accp[8 * q + 6], accp[8 * q + 7]);
    dst[q] = v;
  }
  u16* gbase = Gv + (size_t)b * CH * NN + m;
#pragma unroll
  for (int q = 0; q < 32; q++) {
    gbase[(size_t)(2 * i0 + q) * NN] = f2bf(accg[q]);
  }
}

// ---------------- K2: S_T[m,n] = sum_k Pv[k,m] Tv[k,n]; E=exp(S-40) bf16; den[m]=sum_n E ----------------
__global__ __launch_bounds__(256) void k_scores(const u16* __restrict__ Tt,
                                                const u16* __restrict__ Pt,
                                                u16* __restrict__ E,
                                                float* __restrict__ den,
                                                int b0) {
  const int tid = threadIdx.x;
  const int w = tid >> 6, l = tid & 63, lr = l & 15, lg = l >> 4;
  const int eb = blockIdx.y;
  const int b = b0 + eb;
  const int m0 = blockIdx.x * 64;
  const u16* PtB = Pt + (size_t)b * NN * CH;
  const u16* TtB = Tt + (size_t)b * NN * CH;
  u16* Eb = E + (size_t)eb * NN * NN;
  const f32x4 zero4 = {0.f, 0.f, 0.f, 0.f};

  short8 afr[4][4];
#pragma unroll
  for (int fm = 0; fm < 4; fm++) {
#pragma unroll
    for (int ks = 0; ks < 4; ks++) {
      afr[fm][ks] = *(const short8*)(PtB + (size_t)(m0 + fm * 16 + lr) * CH + ks * 32 + lg * 8);
    }
  }
  float denacc[4][4];
#pragma unroll
  for (int fm = 0; fm < 4; fm++) {
#pragma unroll
    for (int j = 0; j < 4; j++) denacc[fm][j] = 0.f;
  }

  short8 bcur[2][4], bnxt[2][4];
  {
    const int n0 = w * 32;
#pragma unroll
    for (int fn = 0; fn < 2; fn++) {
#pragma unroll
      for (int ks = 0; ks < 4; ks++) {
        bcur[fn][ks] = *(const short8*)(TtB + (size_t)(n0 + fn * 16 + lr) * CH + ks * 32 + lg * 8);
      }
    }
  }
  for (int tt = 0; tt < 36; tt++) {
    if (tt + 1 < 36) {
      const int n1 = (w + 4 * (tt + 1)) * 32;
#pragma unroll
      for (int fn = 0; fn < 2; fn++) {
#pragma unroll
        for (int ks = 0; ks < 4; ks++) {
          bnxt[fn][ks] = *(const short8*)(TtB + (size_t)(n1 + fn * 16 + lr) * CH + ks * 32 + lg * 8);
        }
      }
    }
    f32x4 sacc[4][2];
#pragma unroll
    for (int fm = 0; fm < 4; fm++) {
#pragma unroll
      for (int fn = 0; fn < 2; fn++) sacc[fm][fn] = zero4;
    }
#pragma unroll
    for (int ks = 0; ks < 4; ks++) {
#pragma unroll
      for (int fm = 0; fm < 4; fm++) {
#pragma unroll
        for (int fn = 0; fn < 2; fn++) {
          sacc[fm][fn] = __builtin_amdgcn_mfma_f32_16x16x32_bf16(afr[fm][ks], bcur[fn][ks], sacc[fm][fn], 0, 0, 0);
        }
      }
    }
    const int n0 = (w + 4 * tt) * 32;
#pragma unroll
    for (int fm = 0; fm < 4; fm++) {
#pragma unroll
      for (int fn = 0; fn < 2; fn++) {
        const int n = n0 + fn * 16 + lr;
        float e0 = exp2f((sacc[fm][fn][0] - 40.f) * 1.44269504f);
        float e1 = exp2f((sacc[fm][fn][1] - 40.f) * 1.44269504f);
        float e2 = exp2f((sacc[fm][fn][2] - 40.f) * 1.44269504f);
        float e3 = exp2f((sacc[fm][fn][3] - 40.f) * 1.44269504f);
        denacc[fm][0] += e0;
        denacc[fm][1] += e1;
        denacc[fm][2] += e2;
        denacc[fm][3] += e3;
        uint2 pk;
        pk.x = packbf(e0, e1);
        pk.y = packbf(e2, e3);
        *(uint2*)(Eb + (size_t)n * NN + (m0 + fm * 16 + lg * 4)) = pk;
      }
    }
    if (tt + 1 < 36) {
#pragma unroll
      for (int fn = 0; fn < 2; fn++) {
#pragma unroll
        for (int ks = 0; ks < 4; ks++) bcur[fn][ks] = bnxt[fn][ks];
      }
    }
  }
#pragma unroll
  for (int fm = 0; fm < 4; fm++) {
#pragma unroll
    for (int j = 0; j < 4; j++) {
      float v = denacc[fm][j];
      v += __shfl_xor(v, 1, 64);
      v += __shfl_xor(v, 2, 64);
      v += __shfl_xor(v, 4, 64);
      v += __shfl_xor(v, 8, 64);
      denacc[fm][j] = v;
    }
  }
  __shared__ float dpart[4][64];
  if (lr == 0) {
#pragma unroll
    for (int fm = 0; fm < 4; fm++) {
#pragma unroll
      for (int j = 0; j < 4; j++) dpart[w][fm * 16 + lg * 4 + j] = denacc[fm][j];
    }
  }
  __syncthreads();
  if (tid < 64) {
    den[b * NN + m0 + tid] = dpart[0][tid] + dpart[1][tid] + dpart[2][tid] + dpart[3][tid];
  }
}

// ---------------- K2b: Gd = Gv / den[m] ----------------
__global__ __launch_bounds__(256) void k_gd(const u16* __restrict__ Gv,
                                            const float* __restrict__ den,
                                            u16* __restrict__ Gd,
                                            int b0) {
  size_t base = (size_t)b0 * CH * NN;
  size_t i8 = base + ((size_t)blockIdx.x * 256 + threadIdx.x) * 8;
  int m = (int)(i8 % NN);
  int b = (int)(i8 / ((size_t)CH * NN));
  uint4 v = *(const uint4*)(Gv + i8);
  const float* dn = den + b * NN + m;
  u32 vv[4] = {v.x, v.y, v.z, v.w};
  float o[8];
#pragma unroll
  for (int q = 0; q < 4; q++) {
    float lo = bf2f((u16)(vv[q] & 0xffffu));
    float hi = bf2f((u16)(vv[q] >> 16));
    o[2 * q] = lo / dn[2 * q];
    o[2 * q + 1] = hi / dn[2 * q + 1];
  }
  uint4 ov;
  ov.x = packbf(o[0], o[1]);
  ov.y = packbf(o[2], o[3]);
  ov.z = packbf(o[4], o[5]);
  ov.w = packbf(o[6], o[7]);
  *(uint4*)(Gd + i8) = ov;
}

// ---------------- K3: Yt = Gd @ E^T (K=4608), then out = Wm @ yy + x1 fused ----------------
__global__ __launch_bounds__(256) void k_pv_out(const u16* __restrict__ E,
                                                const u16* __restrict__ Gd,
                                                const u16* __restrict__ wmb,
                                                const float* __restrict__ x1,
                                                float* __restrict__ out,
                                                int b0) {
  __shared__ u16 yyT[128][72];  // [p_local][i], padded row 72 (144B) to dodge bank conflicts
  const int tid = threadIdx.x;
  const int w = tid >> 6, l = tid & 63, lr = l & 15, lg = l >> 4;
  const int eb = blockIdx.y;
  const int b = b0 + eb;
  const int nt0 = blockIdx.x * 64;
  const int wc = w >> 1, wn = w & 1;
  const int cc0 = wc * 64;
  const int n0 = nt0 + wn * 32;
  const u16* Eb = E + (size_t)eb * NN * NN;
  const u16* Gb = Gd + (size_t)b * CH * NN;
  const f32x4 zero4 = {0.f, 0.f, 0.f, 0.f};

  f32x4 acc[4][2];
#pragma unroll
  for (int fa = 0; fa < 4; fa++) {
#pragma unroll
    for (int fb = 0; fb < 2; fb++) acc[fa][fb] = zero4;
  }

  short8 Ac[4], Bc[2], An[4], Bn[2];
#pragma unroll
  for (int fa = 0; fa < 4; fa++)
    Ac[fa] = *(const short8*)(Gb + (size_t)(cc0 + fa * 16 + lr) * NN + lg * 8);
#pragma unroll
  for (int fb = 0; fb < 2; fb++)
    Bc[fb] = *(const short8*)(Eb + (size_t)(n0 + fb * 16 + lr) * NN + lg * 8);

  for (int ks = 0; ks < 144; ks++) {
    const int mn = (ks + 1) * 32;
    if (ks + 1 < 144) {
#pragma unroll
      for (int fa = 0; fa < 4; fa++)
        An[fa] = *(const short8*)(Gb + (size_t)(cc0 + fa * 16 + lr) * NN + mn + lg * 8);
#pragma unroll
      for (int fb = 0; fb < 2; fb++)
        Bn[fb] = *(const short8*)(Eb + (size_t)(n0 + fb * 16 + lr) * NN + mn + lg * 8);
    }
#pragma unroll
    for (int fa = 0; fa < 4; fa++) {
#pragma unroll
      for (int fb = 0; fb < 2; fb++) {
        acc[fa][fb] = __builtin_amdgcn_mfma_f32_16x16x32_bf16(Ac[fa], Bc[fb], acc[fa][fb], 0, 0, 0);
      }
    }
    if (ks + 1 < 144) {
#pragma unroll
      for (int fa = 0; fa < 4; fa++) Ac[fa] = An[fa];
#pragma unroll
      for (int fb = 0; fb < 2; fb++) Bc[fb] = Bn[fb];
    }
  }
  // scatter Yt tile to LDS as yy (bf16): yyT[h*64 + n_local][i], cc = 2i+h
#pragma unroll
  for (int fa = 0; fa < 4; fa++) {
#pragma unroll
    for (int fb = 0; fb < 2; fb++) {
      const int nl = wn * 32 + fb * 16 + lr;
#pragma unroll
      for (int j = 0; j < 4; j++) {
        const int cc = cc0 + fa * 16 + lg * 4 + j;
        const int i = cc >> 1, h = cc & 1;
        yyT[h * 64 + nl][i] = f2bf(acc[fa][fb][j]);
      }
    }
  }
  __syncthreads();
  // epilogue: out[c, p] = sum_i Wm[c,i]*yy[i,p] + x1[c,p]
  f32x4 eacc[4][4];
#pragma unroll
  for (int fa = 0; fa < 4; fa++) {
#pragma unroll
    for (int fb = 0; fb < 4; fb++) eacc[fa][fb] = zero4;
  }
  const int ec = wc, ep = wn;
#pragma unroll
  for (int ks = 0; ks < 2; ks++) {
    short8 wa[4];
#pragma unroll
    for (int fa = 0; fa < 4; fa++)
      wa[fa] = *(const short8*)(wmb + (ec * 64 + fa * 16 + lr) * 64 + ks * 32 + lg * 8);
    short8 yb[4];
#pragma unroll
    for (int fb = 0; fb < 4; fb++)
      yb[fb] = *(const short8*)(&yyT[ep * 64 + fb * 16 + lr][ks * 32 + lg * 8]);
#pragma unroll
    for (int fa = 0; fa < 4; fa++) {
#pragma unroll
      for (int fb = 0; fb < 4; fb++) {
        eacc[fa][fb] = __builtin_amdgcn_mfma_f32_16x16x32_bf16(wa[fa], yb[fb], eacc[fa][fb], 0, 0, 0);
      }
    }
  }
  const float* x1b = x1 + (size_t)b * CH * HW2;
  float* ob = out + (size_t)b * CH * HW2;
#pragma unroll
  for (int fa = 0; fa < 4; fa++) {
#pragma unroll
    for (int fb = 0; fb < 4; fb++) {
      const int pl = ep * 64 + fb * 16 + lr;
      const int pg = (pl & 63) + nt0 + (pl >> 6) * NN;
#pragma unroll
      for (int j = 0; j < 4; j++) {
        const int c = ec * 64 + fa * 16 + lg * 4 + j;
        const size_t o = (size_t)c * HW2 + pg;
        ob[o] = eacc[fa][fb][j] + x1b[o];
      }
    }
  }
}

extern "C" void kernel_launch(void* const* d_in, const int* in_sizes, int n_in,
                              void* d_out, int out_size, void* d_ws, size_t ws_size,
                              hipStream_t stream) {
  const float* x1 = (const float*)d_in[0];
  const float* x2 = (const float*)d_in[1];
  const float* wt = (const float*)d_in[2];
  const float* wp = (const float*)d_in[3];
  const float* wg = (const float*)d_in[4];
  const float* wm = (const float*)d_in[5];
  float* out = (float*)d_out;

  char* ws = (char*)d_ws;
  const size_t SZ_T = (size_t)NB * NN * CH * 2;  // 4,718,592 B each
  u16* Tt = (u16*)ws; ws += SZ_T;
  u16* Pt = (u16*)ws; ws += SZ_T;
  u16* Gv = (u16*)ws; ws += SZ_T;
  u16* Gd = (u16*)ws; ws += SZ_T;
  float* den = (float*)ws; ws += (size_t)NB * NN * 4;
  u16* wmb = (u16*)ws; ws += (size_t)CH * INTER2 * 2;
  u16* E = (u16*)ws;

  const size_t fixed = (size_t)(ws - (char*)d_ws);
  const size_t eslab = (size_t)NN * NN * 2;  // 42,467,328 B per batch slab
  int eslots = 0;
  if (ws_size >= fixed + 4 * eslab) eslots = 4;
  else if (ws_size >= fixed + 2 * eslab) eslots = 2;
  else if (ws_size >= fixed + 1 * eslab) eslots = 1;
  if (eslots == 0) return;  // insufficient workspace; will show as untouched output

  hipLaunchKernelGGL(k_wcvt, dim3(32), dim3(256), 0, stream, wm, wmb);
  hipLaunchKernelGGL(k_theta, dim3(72, NB), dim3(256), 0, stream, x1, wt, Tt);
  hipLaunchKernelGGL(k_phi_g, dim3(72, NB), dim3(256), 0, stream, x2, wp, wg, Pt, Gv);
  for (int b0 = 0; b0 < NB; b0 += eslots) {
    hipLaunchKernelGGL(k_scores, dim3(72, eslots), dim3(256), 0, stream, Tt, Pt, E, den, b0);
    hipLaunchKernelGGL(k_gd, dim3(288 * eslots), dim3(256), 0, stream, Gv, den, Gd, b0);
    hipLaunchKernelGGL(k_pv_out, dim3(72, eslots), dim3(256), 0, stream, E, Gd, wmb, x1, out, b0);
  }
}

// Round 2
// 397.516 us; speedup vs baseline: 1.1493x; 1.1493x over previous
//
#include <hip/hip_runtime.h>

typedef __attribute__((ext_vector_type(8))) short short8;
typedef __attribute__((ext_vector_type(4))) float f32x4;
typedef unsigned short u16;
typedef unsigned int u32;

#define NB 4
#define CH 128
#define INTER2 64
#define HW2 9216
#define NN 4608
#define NSL 1152  // NN/4 n-slice for k_scores / K-slice for k_pv

__device__ __forceinline__ u16 f2bf(float f) {
  u32 u = __float_as_uint(f);
  u += 0x7fffu + ((u >> 16) & 1u);
  return (u16)(u >> 16);
}
__device__ __forceinline__ float bf2f(u16 h) { return __uint_as_float(((u32)h) << 16); }
__device__ __forceinline__ u32 packbf(float a, float b) {
  return (u32)f2bf(a) | ((u32)f2bf(b) << 16);
}

// ---------------- K0: w_mask f32 -> bf16 ----------------
__global__ void k_wcvt(const float* __restrict__ wm, u16* __restrict__ wmb) {
  int i = blockIdx.x * 256 + threadIdx.x;
  if (i < CH * INTER2) wmb[i] = f2bf(wm[i]);
}

// ---------------- K1a: theta = w_theta @ x1, stored transposed Tt[b][n][cc] ----------------
// block: 64 n x 32 i (i-half by blockIdx.x&1). grid (144, NB).
__global__ __launch_bounds__(256) void k_theta(const float* __restrict__ x1,
                                               const float* __restrict__ wt,
                                               u16* __restrict__ Tt) {
  __shared__ float wT[CH][32];
  const int tid = threadIdx.x;
  const int ih = blockIdx.x & 1, nt = blockIdx.x >> 1;
  for (int idx = tid; idx < 32 * CH; idx += 256) {
    int ii = idx >> 7, c = idx & 127;
    wT[c][ii] = wt[(ih * 32 + ii) * CH + c];
  }
  __syncthreads();
  const int nl = tid & 63, grp = tid >> 6;
  const int b = blockIdx.y;
  const int n = nt * 64 + nl;
  const float* X = x1 + (size_t)b * CH * HW2 + n;
  const int iL = grp * 8;
  float acc[16];
#pragma unroll
  for (int q = 0; q < 16; q++) acc[q] = 0.f;
  float xa = X[0], xb = X[NN];
  for (int c = 0; c < CH; c++) {
    float xa2 = 0.f, xb2 = 0.f;
    if (c + 1 < CH) { xa2 = X[(size_t)(c + 1) * HW2]; xb2 = X[(size_t)(c + 1) * HW2 + NN]; }
#pragma unroll
    for (int ii = 0; ii < 8; ii++) {
      float wv = wT[c][iL + ii];
      acc[2 * ii] += wv * xa;
      acc[2 * ii + 1] += wv * xb;
    }
    xa = xa2; xb = xb2;
  }
  uint4* dst = (uint4*)(Tt + ((size_t)b * NN + n) * CH + 2 * (ih * 32 + iL));
#pragma unroll
  for (int q = 0; q < 2; q++) {
    uint4 v;
    v.x = packbf(acc[8 * q + 0], acc[8 * q + 1]);
    v.y = packbf(acc[8 * q + 2], acc[8 * q + 3]);
    v.z = packbf(acc[8 * q + 4], acc[8 * q + 5]);
    v.w = packbf(acc[8 * q + 6], acc[8 * q + 7]);
    dst[q] = v;
  }
}

// ---------------- K1bc: phi -> Pt[b][m][cc], g -> Gt[b][m][cc] (both transposed, coalesced) ----------------
__global__ __launch_bounds__(256) void k_phi_g(const float* __restrict__ x2,
                                               const float* __restrict__ wp,
                                               const float* __restrict__ wg,
                                               u16* __restrict__ Pt,
                                               u16* __restrict__ Gt) {
  __shared__ float wpT[CH][32];
  __shared__ float wgT[CH][32];
  const int tid = threadIdx.x;
  const int ih = blockIdx.x & 1, nt = blockIdx.x >> 1;
  for (int idx = tid; idx < 32 * CH; idx += 256) {
    int ii = idx >> 7, c = idx & 127;
    wpT[c][ii] = wp[(ih * 32 + ii) * CH + c];
    wgT[c][ii] = wg[(ih * 32 + ii) * CH + c];
  }
  __syncthreads();
  const int ml = tid & 63, grp = tid >> 6;
  const int b = blockIdx.y;
  const int m = nt * 64 + ml;
  const float* X = x2 + (size_t)b * CH * HW2 + m;
  const int iL = grp * 8;
  float accp[16], accg[16];
#pragma unroll
  for (int q = 0; q < 16; q++) { accp[q] = 0.f; accg[q] = 0.f; }
  float xa = X[0], xb = X[NN];
  for (int c = 0; c < CH; c++) {
    float xa2 = 0.f, xb2 = 0.f;
    if (c + 1 < CH) { xa2 = X[(size_t)(c + 1) * HW2]; xb2 = X[(size_t)(c + 1) * HW2 + NN]; }
#pragma unroll
    for (int ii = 0; ii < 8; ii++) {
      float wv = wpT[c][iL + ii];
      accp[2 * ii] += wv * xa;
      accp[2 * ii + 1] += wv * xb;
      float gv = wgT[c][iL + ii];
      accg[2 * ii] += gv * xa;
      accg[2 * ii + 1] += gv * xb;
    }
    xa = xa2; xb = xb2;
  }
  uint4* dp = (uint4*)(Pt + ((size_t)b * NN + m) * CH + 2 * (ih * 32 + iL));
  uint4* dg = (uint4*)(Gt + ((size_t)b * NN + m) * CH + 2 * (ih * 32 + iL));
#pragma unroll
  for (int q = 0; q < 2; q++) {
    uint4 v;
    v.x = packbf(accp[8 * q + 0], accp[8 * q + 1]);
    v.y = packbf(accp[8 * q + 2], accp[8 * q + 3]);
    v.z = packbf(accp[8 * q + 4], accp[8 * q + 5]);
    v.w = packbf(accp[8 * q + 6], accp[8 * q + 7]);
    dp[q] = v;
    uint4 g;
    g.x = packbf(accg[8 * q + 0], accg[8 * q + 1]);
    g.y = packbf(accg[8 * q + 2], accg[8 * q + 3]);
    g.z = packbf(accg[8 * q + 4], accg[8 * q + 5]);
    g.w = packbf(accg[8 * q + 6], accg[8 * q + 7]);
    dg[q] = g;
  }
}

// ---------------- K2: E[n][m]=exp(S-40) bf16; denp[s][b][m]=partial sum over n-slice ----------------
// grid (72 m-tiles, 4 n-slices, eslots)
__global__ __launch_bounds__(256) void k_scores(const u16* __restrict__ Tt,
                                                const u16* __restrict__ Pt,
                                                u16* __restrict__ E,
                                                float* __restrict__ denp,
                                                int b0) {
  const int tid = threadIdx.x;
  const int w = tid >> 6, l = tid & 63, lr = l & 15, lg = l >> 4;
  const int s = blockIdx.y;
  const int eb = blockIdx.z;
  const int b = b0 + eb;
  const int m0 = blockIdx.x * 64;
  const int n00 = s * NSL;
  const u16* PtB = Pt + (size_t)b * NN * CH;
  const u16* TtB = Tt + (size_t)b * NN * CH;
  u16* Eb = E + (size_t)eb * NN * NN;
  const f32x4 zero4 = {0.f, 0.f, 0.f, 0.f};

  short8 afr[4][4];
#pragma unroll
  for (int fm = 0; fm < 4; fm++) {
#pragma unroll
    for (int ks = 0; ks < 4; ks++) {
      afr[fm][ks] = *(const short8*)(PtB + (size_t)(m0 + fm * 16 + lr) * CH + ks * 32 + lg * 8);
    }
  }
  float denacc[4][4];
#pragma unroll
  for (int fm = 0; fm < 4; fm++) {
#pragma unroll
    for (int j = 0; j < 4; j++) denacc[fm][j] = 0.f;
  }

  short8 bcur[2][4], bnxt[2][4];
  {
    const int n0 = n00 + w * 32;
#pragma unroll
    for (int fn = 0; fn < 2; fn++) {
#pragma unroll
      for (int ks = 0; ks < 4; ks++) {
        bcur[fn][ks] = *(const short8*)(TtB + (size_t)(n0 + fn * 16 + lr) * CH + ks * 32 + lg * 8);
      }
    }
  }
  for (int tt = 0; tt < 9; tt++) {
    if (tt + 1 < 9) {
      const int n1 = n00 + (w + 4 * (tt + 1)) * 32;
#pragma unroll
      for (int fn = 0; fn < 2; fn++) {
#pragma unroll
        for (int ks = 0; ks < 4; ks++) {
          bnxt[fn][ks] = *(const short8*)(TtB + (size_t)(n1 + fn * 16 + lr) * CH + ks * 32 + lg * 8);
        }
      }
    }
    f32x4 sacc[4][2];
#pragma unroll
    for (int fm = 0; fm < 4; fm++) {
#pragma unroll
      for (int fn = 0; fn < 2; fn++) sacc[fm][fn] = zero4;
    }
#pragma unroll
    for (int ks = 0; ks < 4; ks++) {
#pragma unroll
      for (int fm = 0; fm < 4; fm++) {
#pragma unroll
        for (int fn = 0; fn < 2; fn++) {
          sacc[fm][fn] = __builtin_amdgcn_mfma_f32_16x16x32_bf16(afr[fm][ks], bcur[fn][ks], sacc[fm][fn], 0, 0, 0);
        }
      }
    }
    const int n0 = n00 + (w + 4 * tt) * 32;
#pragma unroll
    for (int fm = 0; fm < 4; fm++) {
#pragma unroll
      for (int fn = 0; fn < 2; fn++) {
        const int n = n0 + fn * 16 + lr;
        float e0 = exp2f((sacc[fm][fn][0] - 40.f) * 1.44269504f);
        float e1 = exp2f((sacc[fm][fn][1] - 40.f) * 1.44269504f);
        float e2 = exp2f((sacc[fm][fn][2] - 40.f) * 1.44269504f);
        float e3 = exp2f((sacc[fm][fn][3] - 40.f) * 1.44269504f);
        denacc[fm][0] += e0;
        denacc[fm][1] += e1;
        denacc[fm][2] += e2;
        denacc[fm][3] += e3;
        uint2 pk;
        pk.x = packbf(e0, e1);
        pk.y = packbf(e2, e3);
        *(uint2*)(Eb + (size_t)n * NN + (m0 + fm * 16 + lg * 4)) = pk;
      }
    }
    if (tt + 1 < 9) {
#pragma unroll
      for (int fn = 0; fn < 2; fn++) {
#pragma unroll
        for (int ks = 0; ks < 4; ks++) bcur[fn][ks] = bnxt[fn][ks];
      }
    }
  }
#pragma unroll
  for (int fm = 0; fm < 4; fm++) {
#pragma unroll
    for (int j = 0; j < 4; j++) {
      float v = denacc[fm][j];
      v += __shfl_xor(v, 1, 64);
      v += __shfl_xor(v, 2, 64);
      v += __shfl_xor(v, 4, 64);
      v += __shfl_xor(v, 8, 64);
      denacc[fm][j] = v;
    }
  }
  __shared__ float dpart[4][64];
  if (lr == 0) {
#pragma unroll
    for (int fm = 0; fm < 4; fm++) {
#pragma unroll
      for (int j = 0; j < 4; j++) dpart[w][fm * 16 + lg * 4 + j] = denacc[fm][j];
    }
  }
  __syncthreads();
  if (tid < 64) {
    denp[(size_t)(s * NB + b) * NN + m0 + tid] =
        dpart[0][tid] + dpart[1][tid] + dpart[2][tid] + dpart[3][tid];
  }
}

// ---------------- K2b: Gd[b][cc][m] = Gt[b][m][cc] / den[m]  (transpose + normalize) ----------------
// grid (72 m-tiles, 2 cc-halves, eslots)
__global__ __launch_bounds__(256) void k_gd(const u16* __restrict__ Gt,
                                            const float* __restrict__ denp,
                                            u16* __restrict__ Gd,
                                            int b0) {
  const int tid = threadIdx.x;
  const int m = blockIdx.x * 64 + (tid & 63);
  const int cg0 = blockIdx.y * 64 + (tid >> 6) * 16;
  const int b = b0 + blockIdx.z;
  float den = denp[(size_t)(0 * NB + b) * NN + m] + denp[(size_t)(1 * NB + b) * NN + m] +
              denp[(size_t)(2 * NB + b) * NN + m] + denp[(size_t)(3 * NB + b) * NN + m];
  float rd = 1.0f / den;
  const u16* src = Gt + ((size_t)b * NN + m) * CH + cg0;
  uint4 v0 = *(const uint4*)src;
  uint4 v1 = *(const uint4*)(src + 8);
  u32 a[8] = {v0.x, v0.y, v0.z, v0.w, v1.x, v1.y, v1.z, v1.w};
  u16* dst = Gd + (size_t)b * CH * NN + m;
#pragma unroll
  for (int q = 0; q < 8; q++) {
    float lo = bf2f((u16)(a[q] & 0xffffu)) * rd;
    float hi = bf2f((u16)(a[q] >> 16)) * rd;
    dst[(size_t)(cg0 + 2 * q) * NN] = f2bf(lo);
    dst[(size_t)(cg0 + 2 * q + 1) * NN] = f2bf(hi);
  }
}

// ---------------- K3: Yt = Gd @ E^T (K split x4 across waves, LDS reduce), fused mask+residual ----------------
// grid (72 n-tiles, eslots), 1024 threads = 16 waves: (wk 4) x (wc 2) x (wn 2)
__global__ __launch_bounds__(1024, 1) void k_pv_out(const u16* __restrict__ E,
                                                    const u16* __restrict__ Gd,
                                                    const u16* __restrict__ wmb,
                                                    const float* __restrict__ x1,
                                                    float* __restrict__ out,
                                                    int b0) {
  __shared__ float yAcc[CH][64];   // 32 KB
  __shared__ u16 yyP[128][72];     // 18 KB, 16B-aligned rows
  const int tid = threadIdx.x;
  const int w = tid >> 6, l = tid & 63, lr = l & 15, lg = l >> 4;
  const int eb = blockIdx.y, b = b0 + eb;
  const int nt0 = blockIdx.x * 64;
  const int wk = w >> 2, wc = (w >> 1) & 1, wn = w & 1;
  for (int i = tid; i < CH * 64; i += 1024) ((float*)yAcc)[i] = 0.f;
  __syncthreads();
  const u16* Eb = E + (size_t)eb * NN * NN;
  const u16* Gb = Gd + (size_t)b * CH * NN;
  const int cc0 = wc * 64;
  const int n0 = nt0 + wn * 32;
  const int k0 = wk * NSL;
  const f32x4 zero4 = {0.f, 0.f, 0.f, 0.f};

  f32x4 acc[4][2];
#pragma unroll
  for (int fa = 0; fa < 4; fa++) {
#pragma unroll
    for (int fb = 0; fb < 2; fb++) acc[fa][fb] = zero4;
  }
  short8 Ac[4], Bc[2], An[4], Bn[2];
#pragma unroll
  for (int fa = 0; fa < 4; fa++)
    Ac[fa] = *(const short8*)(Gb + (size_t)(cc0 + fa * 16 + lr) * NN + k0 + lg * 8);
#pragma unroll
  for (int fb = 0; fb < 2; fb++)
    Bc[fb] = *(const short8*)(Eb + (size_t)(n0 + fb * 16 + lr) * NN + k0 + lg * 8);

  for (int ks = 0; ks < 36; ks++) {
    if (ks + 1 < 36) {
      const int kk = k0 + (ks + 1) * 32 + lg * 8;
#pragma unroll
      for (int fa = 0; fa < 4; fa++)
        An[fa] = *(const short8*)(Gb + (size_t)(cc0 + fa * 16 + lr) * NN + kk);
#pragma unroll
      for (int fb = 0; fb < 2; fb++)
        Bn[fb] = *(const short8*)(Eb + (size_t)(n0 + fb * 16 + lr) * NN + kk);
    }
#pragma unroll
    for (int fa = 0; fa < 4; fa++) {
#pragma unroll
      for (int fb = 0; fb < 2; fb++) {
        acc[fa][fb] = __builtin_amdgcn_mfma_f32_16x16x32_bf16(Ac[fa], Bc[fb], acc[fa][fb], 0, 0, 0);
      }
    }
    if (ks + 1 < 36) {
#pragma unroll
      for (int fa = 0; fa < 4; fa++) Ac[fa] = An[fa];
#pragma unroll
      for (int fb = 0; fb < 2; fb++) Bc[fb] = Bn[fb];
    }
  }
  // K-slice reduction into LDS
#pragma unroll
  for (int fa = 0; fa < 4; fa++) {
#pragma unroll
    for (int fb = 0; fb < 2; fb++) {
#pragma unroll
      for (int j = 0; j < 4; j++) {
        atomicAdd(&yAcc[cc0 + fa * 16 + lg * 4 + j][wn * 32 + fb * 16 + lr], acc[fa][fb][j]);
      }
    }
  }
  __syncthreads();
  // transpose to yy[p][i] bf16: cc = 2i+h, p = h*64 + n_local
  {
    const int n = tid & 63, cg = tid >> 6;
#pragma unroll
    for (int q = 0; q < 8; q++) {
      int cc = cg * 8 + q;
      yyP[(cc & 1) * 64 + n][cc >> 1] = f2bf(yAcc[cc][n]);
    }
  }
  __syncthreads();
  // epilogue: out[c,p] = Wm[c,:] @ yy[:,p] + x1[c,p], 8 waves
  if (w < 8) {
    const int wc2 = w >> 2, wp2 = w & 3;
    f32x4 eacc[4][2];
#pragma unroll
    for (int fa = 0; fa < 4; fa++) {
#pragma unroll
      for (int fb = 0; fb < 2; fb++) eacc[fa][fb] = zero4;
    }
#pragma unroll
    for (int ks = 0; ks < 2; ks++) {
      short8 wa[4];
#pragma unroll
      for (int fa = 0; fa < 4; fa++)
        wa[fa] = *(const short8*)(wmb + (wc2 * 64 + fa * 16 + lr) * 64 + ks * 32 + lg * 8);
      short8 yb[2];
#pragma unroll
      for (int fb = 0; fb < 2; fb++)
        yb[fb] = *(const short8*)(&yyP[wp2 * 32 + fb * 16 + lr][ks * 32 + lg * 8]);
#pragma unroll
      for (int fa = 0; fa < 4; fa++) {
#pragma unroll
        for (int fb = 0; fb < 2; fb++) {
          eacc[fa][fb] = __builtin_amdgcn_mfma_f32_16x16x32_bf16(wa[fa], yb[fb], eacc[fa][fb], 0, 0, 0);
        }
      }
    }
    const float* x1b = x1 + (size_t)b * CH * HW2;
    float* ob = out + (size_t)b * CH * HW2;
#pragma unroll
    for (int fa = 0; fa < 4; fa++) {
#pragma unroll
      for (int fb = 0; fb < 2; fb++) {
        const int pl = wp2 * 32 + fb * 16 + lr;
        const int pg = (pl & 63) + nt0 + (pl >> 6) * NN;
#pragma unroll
        for (int j = 0; j < 4; j++) {
          const int c = wc2 * 64 + fa * 16 + lg * 4 + j;
          const size_t o = (size_t)c * HW2 + pg;
          ob[o] = eacc[fa][fb][j] + x1b[o];
        }
      }
    }
  }
}

extern "C" void kernel_launch(void* const* d_in, const int* in_sizes, int n_in,
                              void* d_out, int out_size, void* d_ws, size_t ws_size,
                              hipStream_t stream) {
  const float* x1 = (const float*)d_in[0];
  const float* x2 = (const float*)d_in[1];
  const float* wt = (const float*)d_in[2];
  const float* wp = (const float*)d_in[3];
  const float* wg = (const float*)d_in[4];
  const float* wm = (const float*)d_in[5];
  float* out = (float*)d_out;

  char* ws = (char*)d_ws;
  const size_t SZ_T = (size_t)NB * NN * CH * 2;
  u16* Tt = (u16*)ws; ws += SZ_T;
  u16* Pt = (u16*)ws; ws += SZ_T;
  u16* Gt = (u16*)ws; ws += SZ_T;
  u16* Gd = (u16*)ws; ws += SZ_T;
  float* denp = (float*)ws; ws += (size_t)16 * NN * 4;
  u16* wmb = (u16*)ws; ws += (size_t)CH * INTER2 * 2;
  u16* E = (u16*)ws;

  const size_t fixed = (size_t)(ws - (char*)d_ws);
  const size_t eslab = (size_t)NN * NN * 2;
  int eslots = 0;
  if (ws_size >= fixed + 4 * eslab) eslots = 4;
  else if (ws_size >= fixed + 2 * eslab) eslots = 2;
  else if (ws_size >= fixed + 1 * eslab) eslots = 1;
  if (eslots == 0) return;

  hipLaunchKernelGGL(k_wcvt, dim3(32), dim3(256), 0, stream, wm, wmb);
  hipLaunchKernelGGL(k_theta, dim3(144, NB), dim3(256), 0, stream, x1, wt, Tt);
  hipLaunchKernelGGL(k_phi_g, dim3(144, NB), dim3(256), 0, stream, x2, wp, wg, Pt, Gt);
  for (int b0 = 0; b0 < NB; b0 += eslots) {
    hipLaunchKernelGGL(k_scores, dim3(72, 4, eslots), dim3(256), 0, stream, Tt, Pt, E, denp, b0);
    hipLaunchKernelGGL(k_gd, dim3(72, 2, eslots), dim3(256), 0, stream, Gt, denp, Gd, b0);
    hipLaunchKernelGGL(k_pv_out, dim3(72, eslots), dim3(1024), 0, stream, E, Gd, wmb, x1, out, b0);
  }
}

// Round 3
// 266.203 us; speedup vs baseline: 1.7162x; 1.4933x over previous
//
#include <hip/hip_runtime.h>

typedef __attribute__((ext_vector_type(8))) short short8;
typedef __attribute__((ext_vector_type(4))) float f32x4;
typedef __attribute__((ext_vector_type(16))) float f32x16;
typedef unsigned short u16;
typedef unsigned int u32;

#define NB 4
#define CH 128
#define INTER2 64
#define HW2 9216
#define NN 4608
#define NSL 1152
#define SK 8   // K-split for PV; SK*eslots slabs of Yp (<=16)

__device__ __forceinline__ u16 f2bf(float f) {
  u32 u = __float_as_uint(f);
  u += 0x7fffu + ((u >> 16) & 1u);
  return (u16)(u >> 16);
}
__device__ __forceinline__ float bf2f(u16 h) { return __uint_as_float(((u32)h) << 16); }
__device__ __forceinline__ u32 packbf(float a, float b) {
  return (u32)f2bf(a) | ((u32)f2bf(b) << 16);
}
__device__ __forceinline__ void gl_lds16(const u16* g, u16* l) {
  __builtin_amdgcn_global_load_lds(
      (const __attribute__((address_space(1))) unsigned int*)g,
      (__attribute__((address_space(3))) unsigned int*)l, 16, 0, 0);
}

// ---------------- K0: w_mask f32 -> bf16 ----------------
__global__ void k_wcvt(const float* __restrict__ wm, u16* __restrict__ wmb) {
  int i = blockIdx.x * 256 + threadIdx.x;
  if (i < CH * INTER2) wmb[i] = f2bf(wm[i]);
}

// ---------------- K1a: theta -> Tt[b][n][cc] (transposed, k-contiguous) ----------------
__global__ __launch_bounds__(256) void k_theta(const float* __restrict__ x1,
                                               const float* __restrict__ wt,
                                               u16* __restrict__ Tt) {
  __shared__ float wT[CH][32];
  const int tid = threadIdx.x;
  const int ih = blockIdx.x & 1, nt = blockIdx.x >> 1;
  for (int idx = tid; idx < 32 * CH; idx += 256) {
    int ii = idx >> 7, c = idx & 127;
    wT[c][ii] = wt[(ih * 32 + ii) * CH + c];
  }
  __syncthreads();
  const int nl = tid & 63, grp = tid >> 6;
  const int b = blockIdx.y;
  const int n = nt * 64 + nl;
  const float* X = x1 + (size_t)b * CH * HW2 + n;
  const int iL = grp * 8;
  float acc[16];
#pragma unroll
  for (int q = 0; q < 16; q++) acc[q] = 0.f;
  float xa = X[0], xb = X[NN];
  for (int c = 0; c < CH; c++) {
    float xa2 = 0.f, xb2 = 0.f;
    if (c + 1 < CH) { xa2 = X[(size_t)(c + 1) * HW2]; xb2 = X[(size_t)(c + 1) * HW2 + NN]; }
#pragma unroll
    for (int ii = 0; ii < 8; ii++) {
      float wv = wT[c][iL + ii];
      acc[2 * ii] += wv * xa;
      acc[2 * ii + 1] += wv * xb;
    }
    xa = xa2; xb = xb2;
  }
  uint4* dst = (uint4*)(Tt + ((size_t)b * NN + n) * CH + 2 * (ih * 32 + iL));
#pragma unroll
  for (int q = 0; q < 2; q++) {
    uint4 v;
    v.x = packbf(acc[8 * q + 0], acc[8 * q + 1]);
    v.y = packbf(acc[8 * q + 2], acc[8 * q + 3]);
    v.z = packbf(acc[8 * q + 4], acc[8 * q + 5]);
    v.w = packbf(acc[8 * q + 6], acc[8 * q + 7]);
    dst[q] = v;
  }
}

// ---------------- K1bc: phi -> Pt[b][m][cc], g -> Gt[b][m][cc] ----------------
__global__ __launch_bounds__(256) void k_phi_g(const float* __restrict__ x2,
                                               const float* __restrict__ wp,
                                               const float* __restrict__ wg,
                                               u16* __restrict__ Pt,
                                               u16* __restrict__ Gt) {
  __shared__ float wpT[CH][32];
  __shared__ float wgT[CH][32];
  const int tid = threadIdx.x;
  const int ih = blockIdx.x & 1, nt = blockIdx.x >> 1;
  for (int idx = tid; idx < 32 * CH; idx += 256) {
    int ii = idx >> 7, c = idx & 127;
    wpT[c][ii] = wp[(ih * 32 + ii) * CH + c];
    wgT[c][ii] = wg[(ih * 32 + ii) * CH + c];
  }
  __syncthreads();
  const int ml = tid & 63, grp = tid >> 6;
  const int b = blockIdx.y;
  const int m = nt * 64 + ml;
  const float* X = x2 + (size_t)b * CH * HW2 + m;
  const int iL = grp * 8;
  float accp[16], accg[16];
#pragma unroll
  for (int q = 0; q < 16; q++) { accp[q] = 0.f; accg[q] = 0.f; }
  float xa = X[0], xb = X[NN];
  for (int c = 0; c < CH; c++) {
    float xa2 = 0.f, xb2 = 0.f;
    if (c + 1 < CH) { xa2 = X[(size_t)(c + 1) * HW2]; xb2 = X[(size_t)(c + 1) * HW2 + NN]; }
#pragma unroll
    for (int ii = 0; ii < 8; ii++) {
      float wv = wpT[c][iL + ii];
      accp[2 * ii] += wv * xa;
      accp[2 * ii + 1] += wv * xb;
      float gv = wgT[c][iL + ii];
      accg[2 * ii] += gv * xa;
      accg[2 * ii + 1] += gv * xb;
    }
    xa = xa2; xb = xb2;
  }
  uint4* dp = (uint4*)(Pt + ((size_t)b * NN + m) * CH + 2 * (ih * 32 + iL));
  uint4* dg = (uint4*)(Gt + ((size_t)b * NN + m) * CH + 2 * (ih * 32 + iL));
#pragma unroll
  for (int q = 0; q < 2; q++) {
    uint4 v;
    v.x = packbf(accp[8 * q + 0], accp[8 * q + 1]);
    v.y = packbf(accp[8 * q + 2], accp[8 * q + 3]);
    v.z = packbf(accp[8 * q + 4], accp[8 * q + 5]);
    v.w = packbf(accp[8 * q + 6], accp[8 * q + 7]);
    dp[q] = v;
    uint4 g;
    g.x = packbf(accg[8 * q + 0], accg[8 * q + 1]);
    g.y = packbf(accg[8 * q + 2], accg[8 * q + 3]);
    g.z = packbf(accg[8 * q + 4], accg[8 * q + 5]);
    g.w = packbf(accg[8 * q + 6], accg[8 * q + 7]);
    dg[q] = g;
  }
}

// ---------------- K2: 32x32 MFMA, A=Tt(rows n) B=Pt(cols m) -> E[n][m] with 64B-run stores ----------------
// grid (144 m-tiles of 32, 4 n-slices, eslots)
__global__ __launch_bounds__(256) void k_scores(const u16* __restrict__ Tt,
                                                const u16* __restrict__ Pt,
                                                u16* __restrict__ E,
                                                float* __restrict__ denp,
                                                int b0) {
  const int tid = threadIdx.x;
  const int w = tid >> 6, l = tid & 63, lm = l & 31, lh = l >> 5;
  const int s = blockIdx.y, eb = blockIdx.z, b = b0 + eb;
  const int m0 = blockIdx.x * 32;
  const u16* PtB = Pt + (size_t)b * NN * CH;
  const u16* TtB = Tt + (size_t)b * NN * CH;
  u16* Eb = E + (size_t)eb * NN * NN;

  short8 bf[8];
#pragma unroll
  for (int ks = 0; ks < 8; ks++)
    bf[ks] = *(const short8*)(PtB + (size_t)(m0 + lm) * CH + ks * 16 + lh * 8);

  float den_l = 0.f;
  short8 ac[8], an[8];
  {
    const int nb0 = s * NSL + w * 32;
#pragma unroll
    for (int ks = 0; ks < 8; ks++)
      ac[ks] = *(const short8*)(TtB + (size_t)(nb0 + lm) * CH + ks * 16 + lh * 8);
  }
  for (int tt = 0; tt < 9; tt++) {
    if (tt + 1 < 9) {
      const int nb1 = s * NSL + (tt + 1) * 128 + w * 32;
#pragma unroll
      for (int ks = 0; ks < 8; ks++)
        an[ks] = *(const short8*)(TtB + (size_t)(nb1 + lm) * CH + ks * 16 + lh * 8);
    }
    f32x16 acc;
#pragma unroll
    for (int q = 0; q < 16; q++) acc[q] = 0.f;
#pragma unroll
    for (int ks = 0; ks < 8; ks++)
      acc = __builtin_amdgcn_mfma_f32_32x32x16_bf16(ac[ks], bf[ks], acc, 0, 0, 0);
    const int nb = s * NSL + tt * 128 + w * 32;
#pragma unroll
    for (int q = 0; q < 16; q++) {
      const int n = nb + (q & 3) + 8 * (q >> 2) + 4 * lh;
      float e = exp2f((acc[q] - 40.f) * 1.44269504f);
      den_l += e;
      Eb[(size_t)n * NN + m0 + lm] = f2bf(e);
    }
    if (tt + 1 < 9) {
#pragma unroll
      for (int ks = 0; ks < 8; ks++) ac[ks] = an[ks];
    }
  }
  den_l += __shfl_xor(den_l, 32, 64);
  __shared__ float dl[4][32];
  if (l < 32) dl[w][l] = den_l;
  __syncthreads();
  if (tid < 32)
    denp[(size_t)(s * NB + b) * NN + m0 + tid] =
        dl[0][tid] + dl[1][tid] + dl[2][tid] + dl[3][tid];
}

// ---------------- K2b: Gd[b][cc][m] = Gt[b][m][cc] / den[m] ----------------
__global__ __launch_bounds__(256) void k_gd(const u16* __restrict__ Gt,
                                            const float* __restrict__ denp,
                                            u16* __restrict__ Gd,
                                            int b0) {
  const int tid = threadIdx.x;
  const int m = blockIdx.x * 64 + (tid & 63);
  const int cg0 = blockIdx.y * 64 + (tid >> 6) * 16;
  const int b = b0 + blockIdx.z;
  float den = denp[(size_t)(0 * NB + b) * NN + m] + denp[(size_t)(1 * NB + b) * NN + m] +
              denp[(size_t)(2 * NB + b) * NN + m] + denp[(size_t)(3 * NB + b) * NN + m];
  float rd = 1.0f / den;
  const u16* src = Gt + ((size_t)b * NN + m) * CH + cg0;
  uint4 v0 = *(const uint4*)src;
  uint4 v1 = *(const uint4*)(src + 8);
  u32 a[8] = {v0.x, v0.y, v0.z, v0.w, v1.x, v1.y, v1.z, v1.w};
  u16* dst = Gd + (size_t)b * CH * NN + m;
#pragma unroll
  for (int q = 0; q < 8; q++) {
    float lo = bf2f((u16)(a[q] & 0xffffu)) * rd;
    float hi = bf2f((u16)(a[q] >> 16)) * rd;
    dst[(size_t)(cg0 + 2 * q) * NN] = f2bf(lo);
    dst[(size_t)(cg0 + 2 * q + 1) * NN] = f2bf(hi);
  }
}

// ---------------- K3: Yp[slab] = Gd @ E^T (m97-style LDS GEMM, K-split x SK) ----------------
// grid (SK*36, eslots), 256 thr / 4 waves, tile 128c x 128n, BK=64
__global__ __launch_bounds__(256) void k_pv(const u16* __restrict__ E,
                                            const u16* __restrict__ Gd,
                                            float* __restrict__ Yp,
                                            int b0) {
  __shared__ u16 lA[128 * 64];
  __shared__ u16 lB[128 * 64];
  const int tid = threadIdx.x;
  const int w = tid >> 6, l = tid & 63, lr = l & 15, lg = l >> 4;
  const int sk = blockIdx.x / 36, nt = blockIdx.x % 36;
  const int eb = blockIdx.y, b = b0 + eb;
  const int n0 = nt * 128;
  const int k0 = sk * (NN / SK);
  const u16* Eb = E + (size_t)eb * NN * NN;
  const u16* Gb = Gd + (size_t)b * CH * NN;
  const int wm = w >> 1, wn2 = w & 1;
  const int rl = l >> 3;
  const int cg = (l & 7) ^ rl;

  f32x4 acc[4][4];
#pragma unroll
  for (int fa = 0; fa < 4; fa++)
#pragma unroll
    for (int fb = 0; fb < 4; fb++)
#pragma unroll
      for (int j = 0; j < 4; j++) acc[fa][fb][j] = 0.f;

#define STAGE(kk)                                                                   \
  {                                                                                 \
    _Pragma("unroll") for (int r = 0; r < 4; r++) {                                 \
      const int rowA = r * 32 + w * 8 + rl;                                         \
      gl_lds16(Gb + (size_t)rowA * NN + (kk) + cg * 8, &lA[(r * 32 + w * 8) * 64]); \
      gl_lds16(Eb + (size_t)(n0 + rowA) * NN + (kk) + cg * 8,                       \
               &lB[(r * 32 + w * 8) * 64]);                                         \
    }                                                                               \
  }

  STAGE(k0);
  const int NKS = (NN / SK) / 64;  // 9
  for (int st = 0; st < NKS; st++) {
    __syncthreads();
#pragma unroll
    for (int ks2 = 0; ks2 < 2; ks2++) {
      const int cw = ((ks2 * 4 + lg) ^ (lr & 7)) * 8;
      short8 af[4], bfr[4];
#pragma unroll
      for (int fa = 0; fa < 4; fa++)
        af[fa] = *(const short8*)(&lA[(wm * 64 + fa * 16 + lr) * 64 + cw]);
#pragma unroll
      for (int fb = 0; fb < 4; fb++)
        bfr[fb] = *(const short8*)(&lB[(wn2 * 64 + fb * 16 + lr) * 64 + cw]);
#pragma unroll
      for (int fa = 0; fa < 4; fa++)
#pragma unroll
        for (int fb = 0; fb < 4; fb++)
          acc[fa][fb] = __builtin_amdgcn_mfma_f32_16x16x32_bf16(af[fa], bfr[fb], acc[fa][fb], 0, 0, 0);
    }
    __syncthreads();
    if (st + 1 < NKS) STAGE(k0 + (st + 1) * 64);
  }
#undef STAGE
  const int slab = sk * 2 + eb;
  float* Yb = Yp + (size_t)slab * CH * NN;
#pragma unroll
  for (int fa = 0; fa < 4; fa++) {
#pragma unroll
    for (int fb = 0; fb < 4; fb++) {
      const int n = n0 + wn2 * 64 + fb * 16 + lr;
#pragma unroll
      for (int j = 0; j < 4; j++) {
        const int cc = wm * 64 + fa * 16 + lg * 4 + j;
        Yb[(size_t)cc * NN + n] = acc[fa][fb][j];
      }
    }
  }
}

// ---------------- K4: reduce Yp over SK, mask-GEMM + residual ----------------
// grid (144 n-tiles of 32, eslots)
__global__ __launch_bounds__(256) void k_out(const float* __restrict__ Yp,
                                             const u16* __restrict__ wmb,
                                             const float* __restrict__ x1,
                                             float* __restrict__ out,
                                             int b0) {
  __shared__ u16 yy[64][72];
  const int tid = threadIdx.x;
  const int w = tid >> 6, l = tid & 63, lr = l & 15, lg = l >> 4;
  const int eb = blockIdx.y, b = b0 + eb;
  const int n0 = blockIdx.x * 32;
  const int nl = tid & 31, cch = tid >> 5;

  float v[16];
#pragma unroll
  for (int q = 0; q < 16; q++) v[q] = 0.f;
  for (int s2 = 0; s2 < SK; s2++) {
    const float* base = Yp + ((size_t)(s2 * 2 + eb) * CH + cch * 16) * NN + n0 + nl;
#pragma unroll
    for (int q = 0; q < 16; q++) v[q] += base[(size_t)q * NN];
  }
#pragma unroll
  for (int q = 0; q < 16; q++) {
    const int cc = cch * 16 + q;
    yy[(cc & 1) * 32 + nl][cc >> 1] = f2bf(v[q]);
  }
  __syncthreads();

  const int wm3 = w >> 1, wp3 = w & 1;
  f32x4 eacc[4][2];
#pragma unroll
  for (int fa = 0; fa < 4; fa++)
#pragma unroll
    for (int fb = 0; fb < 2; fb++)
#pragma unroll
      for (int j = 0; j < 4; j++) eacc[fa][fb][j] = 0.f;
#pragma unroll
  for (int ks = 0; ks < 2; ks++) {
    short8 wa[4];
#pragma unroll
    for (int fa = 0; fa < 4; fa++)
      wa[fa] = *(const short8*)(wmb + (wm3 * 64 + fa * 16 + lr) * 64 + ks * 32 + lg * 8);
    short8 yb[2];
#pragma unroll
    for (int fb = 0; fb < 2; fb++)
      yb[fb] = *(const short8*)(&yy[wp3 * 32 + fb * 16 + lr][ks * 32 + lg * 8]);
#pragma unroll
    for (int fa = 0; fa < 4; fa++)
#pragma unroll
      for (int fb = 0; fb < 2; fb++)
        eacc[fa][fb] = __builtin_amdgcn_mfma_f32_16x16x32_bf16(wa[fa], yb[fb], eacc[fa][fb], 0, 0, 0);
  }
  const float* x1b = x1 + (size_t)b * CH * HW2;
  float* ob = out + (size_t)b * CH * HW2;
#pragma unroll
  for (int fa = 0; fa < 4; fa++) {
#pragma unroll
    for (int fb = 0; fb < 2; fb++) {
      const int pl = wp3 * 32 + fb * 16 + lr;
      const int col = n0 + (pl & 31) + (pl >> 5) * NN;
#pragma unroll
      for (int j = 0; j < 4; j++) {
        const int c = wm3 * 64 + fa * 16 + lg * 4 + j;
        const size_t o = (size_t)c * HW2 + col;
        ob[o] = eacc[fa][fb][j] + x1b[o];
      }
    }
  }
}

extern "C" void kernel_launch(void* const* d_in, const int* in_sizes, int n_in,
                              void* d_out, int out_size, void* d_ws, size_t ws_size,
                              hipStream_t stream) {
  const float* x1 = (const float*)d_in[0];
  const float* x2 = (const float*)d_in[1];
  const float* wt = (const float*)d_in[2];
  const float* wp = (const float*)d_in[3];
  const float* wg = (const float*)d_in[4];
  const float* wm = (const float*)d_in[5];
  float* out = (float*)d_out;

  char* ws = (char*)d_ws;
  const size_t SZ_T = (size_t)NB * NN * CH * 2;
  u16* Tt = (u16*)ws; ws += SZ_T;
  u16* Pt = (u16*)ws; ws += SZ_T;
  u16* Gt = (u16*)ws; ws += SZ_T;
  u16* Gd = (u16*)ws; ws += SZ_T;
  float* denp = (float*)ws; ws += (size_t)16 * NN * 4;
  u16* wmb = (u16*)ws; ws += (size_t)CH * INTER2 * 2;
  float* Yp = (float*)ws; ws += (size_t)16 * CH * NN * 4;
  u16* E = (u16*)ws;

  const size_t fixed = (size_t)(ws - (char*)d_ws);
  const size_t eslab = (size_t)NN * NN * 2;
  int eslots = 0;
  if (ws_size >= fixed + 2 * eslab) eslots = 2;
  else if (ws_size >= fixed + 1 * eslab) eslots = 1;
  if (eslots == 0) return;

  hipLaunchKernelGGL(k_wcvt, dim3(32), dim3(256), 0, stream, wm, wmb);
  hipLaunchKernelGGL(k_theta, dim3(144, NB), dim3(256), 0, stream, x1, wt, Tt);
  hipLaunchKernelGGL(k_phi_g, dim3(144, NB), dim3(256), 0, stream, x2, wp, wg, Pt, Gt);
  for (int b0 = 0; b0 < NB; b0 += eslots) {
    hipLaunchKernelGGL(k_scores, dim3(144, 4, eslots), dim3(256), 0, stream, Tt, Pt, E, denp, b0);
    hipLaunchKernelGGL(k_gd, dim3(72, 2, eslots), dim3(256), 0, stream, Gt, denp, Gd, b0);
    hipLaunchKernelGGL(k_pv, dim3(SK * 36, eslots), dim3(256), 0, stream, E, Gd, Yp, b0);
    hipLaunchKernelGGL(k_out, dim3(144, eslots), dim3(256), 0, stream, Yp, wmb, x1, out, b0);
  }
}

// Round 4
// 263.315 us; speedup vs baseline: 1.7351x; 1.0110x over previous
//
#include <hip/hip_runtime.h>

typedef __attribute__((ext_vector_type(8))) short short8;
typedef __attribute__((ext_vector_type(4))) float f32x4;
typedef __attribute__((ext_vector_type(16))) float f32x16;
typedef unsigned short u16;
typedef unsigned int u32;

#define NB 4
#define CH 128
#define INTER2 64
#define HW2 9216
#define NN 4608
#define NSL 512   // n-slice for k_scores (9 slices)
#define NSLICE 9
#define SK 8      // K-split for PV

__device__ __forceinline__ u16 f2bf(float f) {
  u32 u = __float_as_uint(f);
  u += 0x7fffu + ((u >> 16) & 1u);
  return (u16)(u >> 16);
}
__device__ __forceinline__ float bf2f(u16 h) { return __uint_as_float(((u32)h) << 16); }
__device__ __forceinline__ u32 packbf(float a, float b) {
  return (u32)f2bf(a) | ((u32)f2bf(b) << 16);
}
__device__ __forceinline__ u32 cvtpk(float lo, float hi) {
  u32 r;
  asm("v_cvt_pk_bf16_f32 %0, %1, %2" : "=v"(r) : "v"(lo), "v"(hi));
  return r;
}
__device__ __forceinline__ void gl_lds16(const u16* g, u16* l) {
  __builtin_amdgcn_global_load_lds(
      (const __attribute__((address_space(1))) unsigned int*)g,
      (__attribute__((address_space(3))) unsigned int*)l, 16, 0, 0);
}

// ---------------- K0: w_mask f32 -> bf16 ----------------
__global__ void k_wcvt(const float* __restrict__ wm, u16* __restrict__ wmb) {
  int i = blockIdx.x * 256 + threadIdx.x;
  if (i < CH * INTER2) wmb[i] = f2bf(wm[i]);
}

// ---------------- K1a: theta -> Tt[b][n][cc] ----------------
__global__ __launch_bounds__(256) void k_theta(const float* __restrict__ x1,
                                               const float* __restrict__ wt,
                                               u16* __restrict__ Tt) {
  __shared__ float wT[CH][33];
  const int tid = threadIdx.x;
  const int ih = blockIdx.x & 1, nt = blockIdx.x >> 1;
  for (int idx = tid; idx < 32 * CH; idx += 256) {
    int ii = idx >> 7, c = idx & 127;
    wT[c][ii] = wt[(ih * 32 + ii) * CH + c];
  }
  __syncthreads();
  const int nl = tid & 63, grp = tid >> 6;
  const int b = blockIdx.y;
  const int n = nt * 64 + nl;
  const float* X = x1 + (size_t)b * CH * HW2 + n;
  const int iL = grp * 8;
  float acc[16];
#pragma unroll
  for (int q = 0; q < 16; q++) acc[q] = 0.f;
  float xa[4], xb[4];
#pragma unroll
  for (int u = 0; u < 4; u++) { xa[u] = X[(size_t)u * HW2]; xb[u] = X[(size_t)u * HW2 + NN]; }
  for (int c = 0; c < CH; c += 4) {
    float xa2[4], xb2[4];
    if (c + 4 < CH) {
#pragma unroll
      for (int u = 0; u < 4; u++) {
        xa2[u] = X[(size_t)(c + 4 + u) * HW2];
        xb2[u] = X[(size_t)(c + 4 + u) * HW2 + NN];
      }
    }
#pragma unroll
    for (int u = 0; u < 4; u++) {
#pragma unroll
      for (int ii = 0; ii < 8; ii++) {
        float wv = wT[c + u][iL + ii];
        acc[2 * ii] += wv * xa[u];
        acc[2 * ii + 1] += wv * xb[u];
      }
    }
    if (c + 4 < CH) {
#pragma unroll
      for (int u = 0; u < 4; u++) { xa[u] = xa2[u]; xb[u] = xb2[u]; }
    }
  }
  uint4* dst = (uint4*)(Tt + ((size_t)b * NN + n) * CH + 2 * (ih * 32 + iL));
#pragma unroll
  for (int q = 0; q < 2; q++) {
    uint4 v;
    v.x = packbf(acc[8 * q + 0], acc[8 * q + 1]);
    v.y = packbf(acc[8 * q + 2], acc[8 * q + 3]);
    v.z = packbf(acc[8 * q + 4], acc[8 * q + 5]);
    v.w = packbf(acc[8 * q + 6], acc[8 * q + 7]);
    dst[q] = v;
  }
}

// ---------------- K1bc: phi -> Pt[b][m][cc], g -> Gt[b][m][cc] ----------------
__global__ __launch_bounds__(256) void k_phi_g(const float* __restrict__ x2,
                                               const float* __restrict__ wp,
                                               const float* __restrict__ wg,
                                               u16* __restrict__ Pt,
                                               u16* __restrict__ Gt) {
  __shared__ float wpT[CH][33];
  __shared__ float wgT[CH][33];
  const int tid = threadIdx.x;
  const int ih = blockIdx.x & 1, nt = blockIdx.x >> 1;
  for (int idx = tid; idx < 32 * CH; idx += 256) {
    int ii = idx >> 7, c = idx & 127;
    wpT[c][ii] = wp[(ih * 32 + ii) * CH + c];
    wgT[c][ii] = wg[(ih * 32 + ii) * CH + c];
  }
  __syncthreads();
  const int ml = tid & 63, grp = tid >> 6;
  const int b = blockIdx.y;
  const int m = nt * 64 + ml;
  const float* X = x2 + (size_t)b * CH * HW2 + m;
  const int iL = grp * 8;
  float accp[16], accg[16];
#pragma unroll
  for (int q = 0; q < 16; q++) { accp[q] = 0.f; accg[q] = 0.f; }
  float xa[4], xb[4];
#pragma unroll
  for (int u = 0; u < 4; u++) { xa[u] = X[(size_t)u * HW2]; xb[u] = X[(size_t)u * HW2 + NN]; }
  for (int c = 0; c < CH; c += 4) {
    float xa2[4], xb2[4];
    if (c + 4 < CH) {
#pragma unroll
      for (int u = 0; u < 4; u++) {
        xa2[u] = X[(size_t)(c + 4 + u) * HW2];
        xb2[u] = X[(size_t)(c + 4 + u) * HW2 + NN];
      }
    }
#pragma unroll
    for (int u = 0; u < 4; u++) {
#pragma unroll
      for (int ii = 0; ii < 8; ii++) {
        float wv = wpT[c + u][iL + ii];
        accp[2 * ii] += wv * xa[u];
        accp[2 * ii + 1] += wv * xb[u];
        float gv = wgT[c + u][iL + ii];
        accg[2 * ii] += gv * xa[u];
        accg[2 * ii + 1] += gv * xb[u];
      }
    }
    if (c + 4 < CH) {
#pragma unroll
      for (int u = 0; u < 4; u++) { xa[u] = xa2[u]; xb[u] = xb2[u]; }
    }
  }
  uint4* dp = (uint4*)(Pt + ((size_t)b * NN + m) * CH + 2 * (ih * 32 + iL));
  uint4* dg = (uint4*)(Gt + ((size_t)b * NN + m) * CH + 2 * (ih * 32 + iL));
#pragma unroll
  for (int q = 0; q < 2; q++) {
    uint4 v;
    v.x = packbf(accp[8 * q + 0], accp[8 * q + 1]);
    v.y = packbf(accp[8 * q + 2], accp[8 * q + 3]);
    v.z = packbf(accp[8 * q + 4], accp[8 * q + 5]);
    v.w = packbf(accp[8 * q + 6], accp[8 * q + 7]);
    dp[q] = v;
    uint4 g;
    g.x = packbf(accg[8 * q + 0], accg[8 * q + 1]);
    g.y = packbf(accg[8 * q + 2], accg[8 * q + 3]);
    g.z = packbf(accg[8 * q + 4], accg[8 * q + 5]);
    g.w = packbf(accg[8 * q + 6], accg[8 * q + 7]);
    dg[q] = g;
  }
}

// ---------------- K2: 32x32 MFMA scores -> E[n][m], denp partials ----------------
// grid (144 m-tiles of 32, 9 n-slices of 512, eslots)
__global__ __launch_bounds__(256) void k_scores(const u16* __restrict__ Tt,
                                                const u16* __restrict__ Pt,
                                                u16* __restrict__ E,
                                                float* __restrict__ denp,
                                                int b0) {
  const int tid = threadIdx.x;
  const int w = tid >> 6, l = tid & 63, lm = l & 31, lh = l >> 5;
  const int s = blockIdx.y, eb = blockIdx.z, b = b0 + eb;
  const int m0 = blockIdx.x * 32;
  const u16* PtB = Pt + (size_t)b * NN * CH;
  const u16* TtB = Tt + (size_t)b * NN * CH;
  u16* Eb = E + (size_t)eb * NN * NN;

  short8 bf[8];
#pragma unroll
  for (int ks = 0; ks < 8; ks++)
    bf[ks] = *(const short8*)(PtB + (size_t)(m0 + lm) * CH + ks * 16 + lh * 8);

  float den_l = 0.f;
  short8 ac[8], an[8];
  {
    const int nb0 = s * NSL + w * 32;
#pragma unroll
    for (int ks = 0; ks < 8; ks++)
      ac[ks] = *(const short8*)(TtB + (size_t)(nb0 + lm) * CH + ks * 16 + lh * 8);
  }
  for (int tt = 0; tt < 4; tt++) {
    if (tt + 1 < 4) {
      const int nb1 = s * NSL + (tt + 1) * 128 + w * 32;
#pragma unroll
      for (int ks = 0; ks < 8; ks++)
        an[ks] = *(const short8*)(TtB + (size_t)(nb1 + lm) * CH + ks * 16 + lh * 8);
    }
    f32x16 acc;
#pragma unroll
    for (int q = 0; q < 16; q++) acc[q] = 0.f;
#pragma unroll
    for (int ks = 0; ks < 8; ks++)
      acc = __builtin_amdgcn_mfma_f32_32x32x16_bf16(ac[ks], bf[ks], acc, 0, 0, 0);
    const int nb = s * NSL + tt * 128 + w * 32;
    // e = 2^(acc*log2e - 40*log2e)
#pragma unroll
    for (int q = 0; q < 16; q += 2) {
      const int n = nb + (q & 3) + 8 * (q >> 2) + 4 * lh;
      float e0 = exp2f(__builtin_fmaf(acc[q], 1.44269504f, -57.70780163f));
      float e1 = exp2f(__builtin_fmaf(acc[q + 1], 1.44269504f, -57.70780163f));
      den_l += e0;
      den_l += e1;
      u32 pk = cvtpk(e0, e1);
      Eb[(size_t)n * NN + m0 + lm] = (u16)pk;
      Eb[(size_t)(n + 1) * NN + m0 + lm] = (u16)(pk >> 16);
    }
    if (tt + 1 < 4) {
#pragma unroll
      for (int ks = 0; ks < 8; ks++) ac[ks] = an[ks];
    }
  }
  den_l += __shfl_xor(den_l, 32, 64);
  __shared__ float dl[4][32];
  if (l < 32) dl[w][l] = den_l;
  __syncthreads();
  if (tid < 32)
    denp[(size_t)(s * NB + b) * NN + m0 + tid] =
        dl[0][tid] + dl[1][tid] + dl[2][tid] + dl[3][tid];
}

// ---------------- K2b: Gd[b][cc][m] = Gt[b][m][cc] / den[m] ----------------
__global__ __launch_bounds__(256) void k_gd(const u16* __restrict__ Gt,
                                            const float* __restrict__ denp,
                                            u16* __restrict__ Gd,
                                            int b0) {
  const int tid = threadIdx.x;
  const int m = blockIdx.x * 64 + (tid & 63);
  const int cg0 = blockIdx.y * 64 + (tid >> 6) * 16;
  const int b = b0 + blockIdx.z;
  float den = 0.f;
#pragma unroll
  for (int s2 = 0; s2 < NSLICE; s2++) den += denp[(size_t)(s2 * NB + b) * NN + m];
  float rd = 1.0f / den;
  const u16* src = Gt + ((size_t)b * NN + m) * CH + cg0;
  uint4 v0 = *(const uint4*)src;
  uint4 v1 = *(const uint4*)(src + 8);
  u32 a[8] = {v0.x, v0.y, v0.z, v0.w, v1.x, v1.y, v1.z, v1.w};
  u16* dst = Gd + (size_t)b * CH * NN + m;
#pragma unroll
  for (int q = 0; q < 8; q++) {
    float lo = bf2f((u16)(a[q] & 0xffffu)) * rd;
    float hi = bf2f((u16)(a[q] >> 16)) * rd;
    dst[(size_t)(cg0 + 2 * q) * NN] = f2bf(lo);
    dst[(size_t)(cg0 + 2 * q + 1) * NN] = f2bf(hi);
  }
}

// ---------------- K3: Yp[slab] = Gd @ E^T (m97-style LDS GEMM, K-split x SK) ----------------
__global__ __launch_bounds__(256) void k_pv(const u16* __restrict__ E,
                                            const u16* __restrict__ Gd,
                                            float* __restrict__ Yp,
                                            int b0) {
  __shared__ u16 lA[128 * 64];
  __shared__ u16 lB[128 * 64];
  const int tid = threadIdx.x;
  const int w = tid >> 6, l = tid & 63, lr = l & 15, lg = l >> 4;
  const int sk = blockIdx.x / 36, nt = blockIdx.x % 36;
  const int eb = blockIdx.y, b = b0 + eb;
  const int n0 = nt * 128;
  const int k0 = sk * (NN / SK);
  const u16* Eb = E + (size_t)eb * NN * NN;
  const u16* Gb = Gd + (size_t)b * CH * NN;
  const int wm = w >> 1, wn2 = w & 1;
  const int rl = l >> 3;
  const int cg = (l & 7) ^ rl;

  f32x4 acc[4][4];
#pragma unroll
  for (int fa = 0; fa < 4; fa++)
#pragma unroll
    for (int fb = 0; fb < 4; fb++)
#pragma unroll
      for (int j = 0; j < 4; j++) acc[fa][fb][j] = 0.f;

#define STAGE(kk)                                                                   \
  {                                                                                 \
    _Pragma("unroll") for (int r = 0; r < 4; r++) {                                 \
      const int rowA = r * 32 + w * 8 + rl;                                         \
      gl_lds16(Gb + (size_t)rowA * NN + (kk) + cg * 8, &lA[(r * 32 + w * 8) * 64]); \
      gl_lds16(Eb + (size_t)(n0 + rowA) * NN + (kk) + cg * 8,                       \
               &lB[(r * 32 + w * 8) * 64]);                                         \
    }                                                                               \
  }

  STAGE(k0);
  const int NKS = (NN / SK) / 64;  // 9
  for (int st = 0; st < NKS; st++) {
    __syncthreads();
#pragma unroll
    for (int ks2 = 0; ks2 < 2; ks2++) {
      const int cw = ((ks2 * 4 + lg) ^ (lr & 7)) * 8;
      short8 af[4], bfr[4];
#pragma unroll
      for (int fa = 0; fa < 4; fa++)
        af[fa] = *(const short8*)(&lA[(wm * 64 + fa * 16 + lr) * 64 + cw]);
#pragma unroll
      for (int fb = 0; fb < 4; fb++)
        bfr[fb] = *(const short8*)(&lB[(wn2 * 64 + fb * 16 + lr) * 64 + cw]);
#pragma unroll
      for (int fa = 0; fa < 4; fa++)
#pragma unroll
        for (int fb = 0; fb < 4; fb++)
          acc[fa][fb] = __builtin_amdgcn_mfma_f32_16x16x32_bf16(af[fa], bfr[fb], acc[fa][fb], 0, 0, 0);
    }
    __syncthreads();
    if (st + 1 < NKS) STAGE(k0 + (st + 1) * 64);
  }
#undef STAGE
  const int slab = sk * 2 + eb;
  float* Yb = Yp + (size_t)slab * CH * NN;
#pragma unroll
  for (int fa = 0; fa < 4; fa++) {
#pragma unroll
    for (int fb = 0; fb < 4; fb++) {
      const int n = n0 + wn2 * 64 + fb * 16 + lr;
#pragma unroll
      for (int j = 0; j < 4; j++) {
        const int cc = wm * 64 + fa * 16 + lg * 4 + j;
        Yb[(size_t)cc * NN + n] = acc[fa][fb][j];
      }
    }
  }
}

// ---------------- K4: reduce Yp over SK, mask-GEMM + residual ----------------
__global__ __launch_bounds__(256) void k_out(const float* __restrict__ Yp,
                                             const u16* __restrict__ wmb,
                                             const float* __restrict__ x1,
                                             float* __restrict__ out,
                                             int b0) {
  __shared__ u16 yy[64][72];
  const int tid = threadIdx.x;
  const int w = tid >> 6, l = tid & 63, lr = l & 15, lg = l >> 4;
  const int eb = blockIdx.y, b = b0 + eb;
  const int n0 = blockIdx.x * 32;
  const int nl = tid & 31, cch = tid >> 5;

  float v[16];
#pragma unroll
  for (int q = 0; q < 16; q++) v[q] = 0.f;
  for (int s2 = 0; s2 < SK; s2++) {
    const float* base = Yp + ((size_t)(s2 * 2 + eb) * CH + cch * 16) * NN + n0 + nl;
#pragma unroll
    for (int q = 0; q < 16; q++) v[q] += base[(size_t)q * NN];
  }
#pragma unroll
  for (int q = 0; q < 16; q++) {
    const int cc = cch * 16 + q;
    yy[(cc & 1) * 32 + nl][cc >> 1] = f2bf(v[q]);
  }
  __syncthreads();

  const int wm3 = w >> 1, wp3 = w & 1;
  f32x4 eacc[4][2];
#pragma unroll
  for (int fa = 0; fa < 4; fa++)
#pragma unroll
    for (int fb = 0; fb < 2; fb++)
#pragma unroll
      for (int j = 0; j < 4; j++) eacc[fa][fb][j] = 0.f;
#pragma unroll
  for (int ks = 0; ks < 2; ks++) {
    short8 wa[4];
#pragma unroll
    for (int fa = 0; fa < 4; fa++)
      wa[fa] = *(const short8*)(wmb + (wm3 * 64 + fa * 16 + lr) * 64 + ks * 32 + lg * 8);
    short8 yb[2];
#pragma unroll
    for (int fb = 0; fb < 2; fb++)
      yb[fb] = *(const short8*)(&yy[wp3 * 32 + fb * 16 + lr][ks * 32 + lg * 8]);
#pragma unroll
    for (int fa = 0; fa < 4; fa++)
#pragma unroll
      for (int fb = 0; fb < 2; fb++)
        eacc[fa][fb] = __builtin_amdgcn_mfma_f32_16x16x32_bf16(wa[fa], yb[fb], eacc[fa][fb], 0, 0, 0);
  }
  const float* x1b = x1 + (size_t)b * CH * HW2;
  float* ob = out + (size_t)b * CH * HW2;
#pragma unroll
  for (int fa = 0; fa < 4; fa++) {
#pragma unroll
    for (int fb = 0; fb < 2; fb++) {
      const int pl = wp3 * 32 + fb * 16 + lr;
      const int col = n0 + (pl & 31) + (pl >> 5) * NN;
#pragma unroll
      for (int j = 0; j < 4; j++) {
        const int c = wm3 * 64 + fa * 16 + lg * 4 + j;
        const size_t o = (size_t)c * HW2 + col;
        ob[o] = eacc[fa][fb][j] + x1b[o];
      }
    }
  }
}

extern "C" void kernel_launch(void* const* d_in, const int* in_sizes, int n_in,
                              void* d_out, int out_size, void* d_ws, size_t ws_size,
                              hipStream_t stream) {
  const float* x1 = (const float*)d_in[0];
  const float* x2 = (const float*)d_in[1];
  const float* wt = (const float*)d_in[2];
  const float* wp = (const float*)d_in[3];
  const float* wg = (const float*)d_in[4];
  const float* wm = (const float*)d_in[5];
  float* out = (float*)d_out;

  char* ws = (char*)d_ws;
  const size_t SZ_T = (size_t)NB * NN * CH * 2;
  u16* Tt = (u16*)ws; ws += SZ_T;
  u16* Pt = (u16*)ws; ws += SZ_T;
  u16* Gt = (u16*)ws; ws += SZ_T;
  u16* Gd = (u16*)ws; ws += SZ_T;
  float* denp = (float*)ws; ws += (size_t)NSLICE * NB * NN * 4;
  u16* wmb = (u16*)ws; ws += (size_t)CH * INTER2 * 2;
  float* Yp = (float*)ws; ws += (size_t)16 * CH * NN * 4;
  u16* E = (u16*)ws;

  const size_t fixed = (size_t)(ws - (char*)d_ws);
  const size_t eslab = (size_t)NN * NN * 2;
  int eslots = 0;
  if (ws_size >= fixed + 2 * eslab) eslots = 2;
  else if (ws_size >= fixed + 1 * eslab) eslots = 1;
  if (eslots == 0) return;

  hipLaunchKernelGGL(k_wcvt, dim3(32), dim3(256), 0, stream, wm, wmb);
  hipLaunchKernelGGL(k_theta, dim3(144, NB), dim3(256), 0, stream, x1, wt, Tt);
  hipLaunchKernelGGL(k_phi_g, dim3(144, NB), dim3(256), 0, stream, x2, wp, wg, Pt, Gt);
  for (int b0 = 0; b0 < NB; b0 += eslots) {
    hipLaunchKernelGGL(k_scores, dim3(144, NSLICE, eslots), dim3(256), 0, stream, Tt, Pt, E, denp, b0);
    hipLaunchKernelGGL(k_gd, dim3(72, 2, eslots), dim3(256), 0, stream, Gt, denp, Gd, b0);
    hipLaunchKernelGGL(k_pv, dim3(SK * 36, eslots), dim3(256), 0, stream, E, Gd, Yp, b0);
    hipLaunchKernelGGL(k_out, dim3(144, eslots), dim3(256), 0, stream, Yp, wmb, x1, out, b0);
  }
}

// Round 5
// 209.145 us; speedup vs baseline: 2.1844x; 1.2590x over previous
//
#include <hip/hip_runtime.h>

typedef __attribute__((ext_vector_type(8))) short short8;
typedef __attribute__((ext_vector_type(4))) float f32x4;
typedef __attribute__((ext_vector_type(16))) float f32x16;
typedef unsigned short u16;
typedef unsigned int u32;

#define NB 4
#define CH 128
#define INTER2 64
#define HW2 9216
#define NN 4608
#define NSLICE 8
#define SLW 576   // n per slice
#define SK 8      // K-split for PV
#define PCH 136   // xT LDS pitch (u16)

__device__ __forceinline__ u16 f2bf(float f) {
  u32 u = __float_as_uint(f);
  u += 0x7fffu + ((u >> 16) & 1u);
  return (u16)(u >> 16);
}
__device__ __forceinline__ float bf2f(u16 h) { return __uint_as_float(((u32)h) << 16); }
__device__ __forceinline__ u32 cvtpk(float lo, float hi) {
  u32 r;
  asm("v_cvt_pk_bf16_f32 %0, %1, %2" : "=v"(r) : "v"(lo), "v"(hi));
  return r;
}
__device__ __forceinline__ void gl_lds16(const u16* g, u16* l) {
  __builtin_amdgcn_global_load_lds(
      (const __attribute__((address_space(1))) unsigned int*)g,
      (__attribute__((address_space(3))) unsigned int*)l, 16, 0, 0);
}

// ---------------- K0: all weights f32 -> bf16 ----------------
__global__ void k_wcvt(const float* __restrict__ wt, const float* __restrict__ wp,
                       const float* __restrict__ wg, const float* __restrict__ wm,
                       u16* __restrict__ wtb, u16* __restrict__ wpb,
                       u16* __restrict__ wgb, u16* __restrict__ wmb) {
  int i = blockIdx.x * 256 + threadIdx.x;
  if (i < CH * INTER2) {
    wtb[i] = f2bf(wt[i]);
    wpb[i] = f2bf(wp[i]);
    wgb[i] = f2bf(wg[i]);
    wmb[i] = f2bf(wm[i]);
  }
}

// ---------------- K1: fused conv GEMM ----------------
// grid (144 p-tiles of 64, NB, 2). z=0: theta(x1)->Tt; z=1: phi,g(x2)->Pt,Gn.
// d-order: d = h*64 + i  (h = p>=NN). Tt/Pt: [n][d] rows 256B. Gn: [d][m].
__global__ __launch_bounds__(256) void k_conv(const float* __restrict__ x1,
                                              const float* __restrict__ x2,
                                              const u16* __restrict__ wtb,
                                              const u16* __restrict__ wpb,
                                              const u16* __restrict__ wgb,
                                              u16* __restrict__ Tt,
                                              u16* __restrict__ Pt,
                                              u16* __restrict__ Gn) {
  __shared__ u16 xT[64 * PCH];  // [p][c] bf16
  __shared__ u16 ot[64 * 72];   // [p][i] out-tile
  const int tid = threadIdx.x;
  const int w = tid >> 6, l = tid & 63, lr = l & 15, lg = l >> 4;
  const int pt = blockIdx.x, b = blockIdx.y, z = blockIdx.z;
  const int p0 = pt * 64;
  const int h = (p0 >= NN) ? 1 : 0;
  const int n0 = p0 - h * NN;
  const float* X = (z ? x2 : x1) + (size_t)b * CH * HW2;

  // stage xT[p][c]
  {
    const int pq = (l & 15) * 4;
    const int cs = w + 4 * (l >> 4);
#pragma unroll
    for (int it = 0; it < 8; it++) {
      const int c = it * 16 + cs;
      float4 v = *(const float4*)(X + (size_t)c * HW2 + p0 + pq);
      xT[(pq + 0) * PCH + c] = f2bf(v.x);
      xT[(pq + 1) * PCH + c] = f2bf(v.y);
      xT[(pq + 2) * PCH + c] = f2bf(v.z);
      xT[(pq + 3) * PCH + c] = f2bf(v.w);
    }
  }
  // weight fragments (shared A/B format): rows w*16+lr
  short8 wsP[4], wsG[4];
  {
    const u16* W1 = z ? wpb : wtb;
#pragma unroll
    for (int ks = 0; ks < 4; ks++)
      wsP[ks] = *(const short8*)(W1 + (w * 16 + lr) * CH + ks * 32 + lg * 8);
    if (z) {
#pragma unroll
      for (int ks = 0; ks < 4; ks++)
        wsG[ks] = *(const short8*)(wgb + (w * 16 + lr) * CH + ks * 32 + lg * 8);
    }
  }
  __syncthreads();
  // x fragments [tp][ks]
  short8 xf[4][4];
#pragma unroll
  for (int tp = 0; tp < 4; tp++)
#pragma unroll
    for (int ks = 0; ks < 4; ks++)
      xf[tp][ks] = *(const short8*)(&xT[(tp * 16 + lr) * PCH + ks * 32 + lg * 8]);

  // P/T part: D[p][i], A=xf (rows p), B=wsP (cols i = w*16+lr)
  f32x4 accP[4];
#pragma unroll
  for (int tp = 0; tp < 4; tp++) {
#pragma unroll
    for (int j = 0; j < 4; j++) accP[tp][j] = 0.f;
#pragma unroll
    for (int ks = 0; ks < 4; ks++)
      accP[tp] = __builtin_amdgcn_mfma_f32_16x16x32_bf16(xf[tp][ks], wsP[ks], accP[tp], 0, 0, 0);
  }
  // write ot[p][i]
#pragma unroll
  for (int tp = 0; tp < 4; tp++) {
#pragma unroll
    for (int j = 0; j < 4; j++)
      ot[(tp * 16 + lg * 4 + j) * 72 + w * 16 + lr] = f2bf(accP[tp][j]);
  }
  // G part: D[i][p], A=wsG (rows i), B=xf (cols p), direct store Gn[d][m]
  if (z) {
    f32x4 accG[4];
#pragma unroll
    for (int tp = 0; tp < 4; tp++) {
#pragma unroll
      for (int j = 0; j < 4; j++) accG[tp][j] = 0.f;
#pragma unroll
      for (int ks = 0; ks < 4; ks++)
        accG[tp] = __builtin_amdgcn_mfma_f32_16x16x32_bf16(wsG[ks], xf[tp][ks], accG[tp], 0, 0, 0);
    }
    u16* Gb = Gn + (size_t)b * CH * NN;
#pragma unroll
    for (int tp = 0; tp < 4; tp++) {
#pragma unroll
      for (int j = 0; j < 4; j++) {
        const int ig = w * 16 + lg * 4 + j;
        Gb[(size_t)((h << 6) + ig) * NN + n0 + tp * 16 + lr] = f2bf(accG[tp][j]);
      }
    }
  }
  __syncthreads();
  // cooperative store of Tt/Pt rows: [n0+p][h*64 .. h*64+63]
  {
    u16* dst = (z ? Pt : Tt) + (size_t)b * NN * CH;
#pragma unroll
    for (int q = 0; q < 2; q++) {
      const int idx = tid * 2 + q;
      const int p = idx >> 3, c8 = (idx & 7) * 8;
      uint4 v = *(const uint4*)(&ot[p * 72 + c8]);
      *(uint4*)(dst + (size_t)(n0 + p) * CH + h * 64 + c8) = v;
    }
  }
}

// ---------------- K2: scores -> E[n][m], denp partials. XCD-pinned n-slices ----------------
// grid (144*8, eslots): x = mt*8 + s  (s -> XCD via round-robin)
__global__ __launch_bounds__(256) void k_scores(const u16* __restrict__ Tt,
                                                const u16* __restrict__ Pt,
                                                u16* __restrict__ E,
                                                float* __restrict__ denp,
                                                int b0) {
  const int tid = threadIdx.x;
  const int w = tid >> 6, l = tid & 63, lm = l & 31, lh = l >> 5;
  const int s = blockIdx.x & 7, mt = blockIdx.x >> 3;
  const int eb = blockIdx.y, b = b0 + eb;
  const int m0 = mt * 32;
  const u16* PtB = Pt + (size_t)b * NN * CH;
  const u16* TtB = Tt + (size_t)b * NN * CH;
  u16* Eb = E + (size_t)eb * NN * NN;
  const int nbase = s * SLW;

  short8 bf[8];
#pragma unroll
  for (int ks = 0; ks < 8; ks++)
    bf[ks] = *(const short8*)(PtB + (size_t)(m0 + lm) * CH + ks * 16 + lh * 8);

  float den_l = 0.f;
  short8 ac[8], an[8];
  int tt = w;
#pragma unroll
  for (int ks = 0; ks < 8; ks++)
    ac[ks] = *(const short8*)(TtB + (size_t)(nbase + tt * 32 + lm) * CH + ks * 16 + lh * 8);
  for (; tt < 18; tt += 4) {
    const int tn = tt + 4;
    if (tn < 18) {
#pragma unroll
      for (int ks = 0; ks < 8; ks++)
        an[ks] = *(const short8*)(TtB + (size_t)(nbase + tn * 32 + lm) * CH + ks * 16 + lh * 8);
    }
    f32x16 acc;
#pragma unroll
    for (int q = 0; q < 16; q++) acc[q] = 0.f;
#pragma unroll
    for (int ks = 0; ks < 8; ks++)
      acc = __builtin_amdgcn_mfma_f32_32x32x16_bf16(ac[ks], bf[ks], acc, 0, 0, 0);
    const int nb = nbase + tt * 32;
#pragma unroll
    for (int q = 0; q < 16; q += 2) {
      const int n = nb + (q & 3) + 8 * (q >> 2) + 4 * lh;
      float e0 = exp2f(__builtin_fmaf(acc[q], 1.44269504f, -57.70780163f));
      float e1 = exp2f(__builtin_fmaf(acc[q + 1], 1.44269504f, -57.70780163f));
      den_l += e0;
      den_l += e1;
      u32 pk = cvtpk(e0, e1);
      Eb[(size_t)n * NN + m0 + lm] = (u16)pk;
      Eb[(size_t)(n + 1) * NN + m0 + lm] = (u16)(pk >> 16);
    }
    if (tn < 18) {
#pragma unroll
      for (int ks = 0; ks < 8; ks++) ac[ks] = an[ks];
    }
  }
  den_l += __shfl_xor(den_l, 32, 64);
  __shared__ float dl[4][32];
  if (l < 32) dl[w][l] = den_l;
  __syncthreads();
  if (tid < 32)
    denp[(size_t)(s * NB + b) * NN + m0 + tid] =
        dl[0][tid] + dl[1][tid] + dl[2][tid] + dl[3][tid];
}

// ---------------- K2b: Gd[d][m] = Gn[d][m] / den[m] (coalesced) ----------------
// grid (288, eslots)
__global__ __launch_bounds__(256) void k_gd(const u16* __restrict__ Gn,
                                            const float* __restrict__ denp,
                                            u16* __restrict__ Gd,
                                            int b0) {
  const int q = blockIdx.x * 256 + threadIdx.x;  // 0..73727
  const int d = q / 576, mc = q % 576;
  const int m0 = mc * 8;
  const int b = b0 + blockIdx.y;
  float dn[8];
#pragma unroll
  for (int i = 0; i < 8; i++) dn[i] = 0.f;
#pragma unroll
  for (int s = 0; s < NSLICE; s++) {
    const float* dp = denp + (size_t)(s * NB + b) * NN + m0;
    float4 a = *(const float4*)dp;
    float4 c = *(const float4*)(dp + 4);
    dn[0] += a.x; dn[1] += a.y; dn[2] += a.z; dn[3] += a.w;
    dn[4] += c.x; dn[5] += c.y; dn[6] += c.z; dn[7] += c.w;
  }
  const size_t off = (size_t)b * CH * NN + (size_t)d * NN + m0;
  uint4 v = *(const uint4*)(Gn + off);
  u32 arr[4] = {v.x, v.y, v.z, v.w};
  uint4 o;
  u32 ov[4];
#pragma unroll
  for (int j = 0; j < 4; j++) {
    float lo = bf2f((u16)(arr[j] & 0xffffu)) / dn[2 * j];
    float hi = bf2f((u16)(arr[j] >> 16)) / dn[2 * j + 1];
    ov[j] = cvtpk(lo, hi);
  }
  o.x = ov[0]; o.y = ov[1]; o.z = ov[2]; o.w = ov[3];
  *(uint4*)(Gd + off) = o;
}

// ---------------- K3: Yp[slab] = Gd @ E^T (m97-style LDS GEMM, K-split x SK) ----------------
__global__ __launch_bounds__(256) void k_pv(const u16* __restrict__ E,
                                            const u16* __restrict__ Gd,
                                            float* __restrict__ Yp,
                                            int b0) {
  __shared__ u16 lA[128 * 64];
  __shared__ u16 lB[128 * 64];
  const int tid = threadIdx.x;
  const int w = tid >> 6, l = tid & 63, lr = l & 15, lg = l >> 4;
  const int sk = blockIdx.x / 36, nt = blockIdx.x % 36;
  const int eb = blockIdx.y, b = b0 + eb;
  const int n0 = nt * 128;
  const int k0 = sk * (NN / SK);
  const u16* Eb = E + (size_t)eb * NN * NN;
  const u16* Gb = Gd + (size_t)b * CH * NN;
  const int wm = w >> 1, wn2 = w & 1;
  const int rl = l >> 3;
  const int cg = (l & 7) ^ rl;

  f32x4 acc[4][4];
#pragma unroll
  for (int fa = 0; fa < 4; fa++)
#pragma unroll
    for (int fb = 0; fb < 4; fb++)
#pragma unroll
      for (int j = 0; j < 4; j++) acc[fa][fb][j] = 0.f;

#define STAGE(kk)                                                                   \
  {                                                                                 \
    _Pragma("unroll") for (int r = 0; r < 4; r++) {                                 \
      const int rowA = r * 32 + w * 8 + rl;                                         \
      gl_lds16(Gb + (size_t)rowA * NN + (kk) + cg * 8, &lA[(r * 32 + w * 8) * 64]); \
      gl_lds16(Eb + (size_t)(n0 + rowA) * NN + (kk) + cg * 8,                       \
               &lB[(r * 32 + w * 8) * 64]);                                         \
    }                                                                               \
  }

  STAGE(k0);
  const int NKS = (NN / SK) / 64;  // 9
  for (int st = 0; st < NKS; st++) {
    __syncthreads();
#pragma unroll
    for (int ks2 = 0; ks2 < 2; ks2++) {
      const int cw = ((ks2 * 4 + lg) ^ (lr & 7)) * 8;
      short8 af[4], bfr[4];
#pragma unroll
      for (int fa = 0; fa < 4; fa++)
        af[fa] = *(const short8*)(&lA[(wm * 64 + fa * 16 + lr) * 64 + cw]);
#pragma unroll
      for (int fb = 0; fb < 4; fb++)
        bfr[fb] = *(const short8*)(&lB[(wn2 * 64 + fb * 16 + lr) * 64 + cw]);
#pragma unroll
      for (int fa = 0; fa < 4; fa++)
#pragma unroll
        for (int fb = 0; fb < 4; fb++)
          acc[fa][fb] = __builtin_amdgcn_mfma_f32_16x16x32_bf16(af[fa], bfr[fb], acc[fa][fb], 0, 0, 0);
    }
    __syncthreads();
    if (st + 1 < NKS) STAGE(k0 + (st + 1) * 64);
  }
#undef STAGE
  const int slab = sk * 2 + eb;
  float* Yb = Yp + (size_t)slab * CH * NN;
#pragma unroll
  for (int fa = 0; fa < 4; fa++) {
#pragma unroll
    for (int fb = 0; fb < 4; fb++) {
      const int n = n0 + wn2 * 64 + fb * 16 + lr;
#pragma unroll
      for (int j = 0; j < 4; j++) {
        const int cc = wm * 64 + fa * 16 + lg * 4 + j;
        Yb[(size_t)cc * NN + n] = acc[fa][fb][j];
      }
    }
  }
}

// ---------------- K4: reduce Yp over SK, mask-GEMM + residual ----------------
__global__ __launch_bounds__(256) void k_out(const float* __restrict__ Yp,
                                             const u16* __restrict__ wmb,
                                             const float* __restrict__ x1,
                                             float* __restrict__ out,
                                             int b0) {
  __shared__ u16 yy[64][72];
  const int tid = threadIdx.x;
  const int w = tid >> 6, l = tid & 63, lr = l & 15, lg = l >> 4;
  const int eb = blockIdx.y, b = b0 + eb;
  const int n0 = blockIdx.x * 32;
  const int nl = tid & 31, cch = tid >> 5;

  float v[16];
#pragma unroll
  for (int q = 0; q < 16; q++) v[q] = 0.f;
  for (int s2 = 0; s2 < SK; s2++) {
    const float* base = Yp + ((size_t)(s2 * 2 + eb) * CH + cch * 16) * NN + n0 + nl;
#pragma unroll
    for (int q = 0; q < 16; q++) v[q] += base[(size_t)q * NN];
  }
#pragma unroll
  for (int q = 0; q < 16; q++) {
    const int d = cch * 16 + q;  // d = h*64 + i
    yy[(d >> 6) * 32 + nl][d & 63] = f2bf(v[q]);
  }
  __syncthreads();

  const int wm3 = w >> 1, wp3 = w & 1;
  f32x4 eacc[4][2];
#pragma unroll
  for (int fa = 0; fa < 4; fa++)
#pragma unroll
    for (int fb = 0; fb < 2; fb++)
#pragma unroll
      for (int j = 0; j < 4; j++) eacc[fa][fb][j] = 0.f;
#pragma unroll
  for (int ks = 0; ks < 2; ks++) {
    short8 wa[4];
#pragma unroll
    for (int fa = 0; fa < 4; fa++)
      wa[fa] = *(const short8*)(wmb + (wm3 * 64 + fa * 16 + lr) * 64 + ks * 32 + lg * 8);
    short8 yb[2];
#pragma unroll
    for (int fb = 0; fb < 2; fb++)
      yb[fb] = *(const short8*)(&yy[wp3 * 32 + fb * 16 + lr][ks * 32 + lg * 8]);
#pragma unroll
    for (int fa = 0; fa < 4; fa++)
#pragma unroll
      for (int fb = 0; fb < 2; fb++)
        eacc[fa][fb] = __builtin_amdgcn_mfma_f32_16x16x32_bf16(wa[fa], yb[fb], eacc[fa][fb], 0, 0, 0);
  }
  const float* x1b = x1 + (size_t)b * CH * HW2;
  float* ob = out + (size_t)b * CH * HW2;
#pragma unroll
  for (int fa = 0; fa < 4; fa++) {
#pragma unroll
    for (int fb = 0; fb < 2; fb++) {
      const int pl = wp3 * 32 + fb * 16 + lr;
      const int col = n0 + (pl & 31) + (pl >> 5) * NN;
#pragma unroll
      for (int j = 0; j < 4; j++) {
        const int c = wm3 * 64 + fa * 16 + lg * 4 + j;
        const size_t o = (size_t)c * HW2 + col;
        ob[o] = eacc[fa][fb][j] + x1b[o];
      }
    }
  }
}

extern "C" void kernel_launch(void* const* d_in, const int* in_sizes, int n_in,
                              void* d_out, int out_size, void* d_ws, size_t ws_size,
                              hipStream_t stream) {
  const float* x1 = (const float*)d_in[0];
  const float* x2 = (const float*)d_in[1];
  const float* wt = (const float*)d_in[2];
  const float* wp = (const float*)d_in[3];
  const float* wg = (const float*)d_in[4];
  const float* wm = (const float*)d_in[5];
  float* out = (float*)d_out;

  char* ws = (char*)d_ws;
  const size_t SZ_T = (size_t)NB * NN * CH * 2;
  u16* Tt = (u16*)ws; ws += SZ_T;
  u16* Pt = (u16*)ws; ws += SZ_T;
  u16* Gn = (u16*)ws; ws += SZ_T;
  u16* Gd = (u16*)ws; ws += SZ_T;
  float* denp = (float*)ws; ws += (size_t)NSLICE * NB * NN * 4;
  u16* wtb = (u16*)ws; ws += (size_t)CH * INTER2 * 2;
  u16* wpb = (u16*)ws; ws += (size_t)CH * INTER2 * 2;
  u16* wgb = (u16*)ws; ws += (size_t)CH * INTER2 * 2;
  u16* wmb = (u16*)ws; ws += (size_t)CH * INTER2 * 2;
  float* Yp = (float*)ws; ws += (size_t)16 * CH * NN * 4;
  u16* E = (u16*)ws;

  const size_t fixed = (size_t)(ws - (char*)d_ws);
  const size_t eslab = (size_t)NN * NN * 2;
  int eslots = 0;
  if (ws_size >= fixed + 2 * eslab) eslots = 2;
  else if (ws_size >= fixed + 1 * eslab) eslots = 1;
  if (eslots == 0) return;

  hipLaunchKernelGGL(k_wcvt, dim3(32), dim3(256), 0, stream, wt, wp, wg, wm, wtb, wpb, wgb, wmb);
  hipLaunchKernelGGL(k_conv, dim3(144, NB, 2), dim3(256), 0, stream, x1, x2, wtb, wpb, wgb, Tt, Pt, Gn);
  for (int b0 = 0; b0 < NB; b0 += eslots) {
    hipLaunchKernelGGL(k_scores, dim3(144 * 8, eslots), dim3(256), 0, stream, Tt, Pt, E, denp, b0);
    hipLaunchKernelGGL(k_gd, dim3(288, eslots), dim3(256), 0, stream, Gn, denp, Gd, b0);
    hipLaunchKernelGGL(k_pv, dim3(SK * 36, eslots), dim3(256), 0, stream, E, Gd, Yp, b0);
    hipLaunchKernelGGL(k_out, dim3(144, eslots), dim3(256), 0, stream, Yp, wmb, x1, out, b0);
  }
}

// Round 6
// 204.455 us; speedup vs baseline: 2.2346x; 1.0229x over previous
//
#include <hip/hip_runtime.h>

typedef __attribute__((ext_vector_type(8))) short short8;
typedef __attribute__((ext_vector_type(4))) float f32x4;
typedef __attribute__((ext_vector_type(16))) float f32x16;
typedef unsigned short u16;
typedef unsigned int u32;

#define NB 4
#define CH 128
#define INTER2 64
#define HW2 9216
#define NN 4608
#define NSLICE 8
#define SLW 576   // n per slice
#define SK 8      // K-split for PV
#define PCH 136   // xT LDS pitch (u16)

__device__ __forceinline__ u16 f2bf(float f) {
  u32 u = __float_as_uint(f);
  u += 0x7fffu + ((u >> 16) & 1u);
  return (u16)(u >> 16);
}
__device__ __forceinline__ float bf2f(u16 h) { return __uint_as_float(((u32)h) << 16); }
__device__ __forceinline__ u32 cvtpk(float lo, float hi) {
  u32 r;
  asm("v_cvt_pk_bf16_f32 %0, %1, %2" : "=v"(r) : "v"(lo), "v"(hi));
  return r;
}
__device__ __forceinline__ void gl_lds16(const u16* g, u16* l) {
  __builtin_amdgcn_global_load_lds(
      (const __attribute__((address_space(1))) unsigned int*)g,
      (__attribute__((address_space(3))) unsigned int*)l, 16, 0, 0);
}

// ---------------- K0: all weights f32 -> bf16 ----------------
__global__ void k_wcvt(const float* __restrict__ wt, const float* __restrict__ wp,
                       const float* __restrict__ wg, const float* __restrict__ wm,
                       u16* __restrict__ wtb, u16* __restrict__ wpb,
                       u16* __restrict__ wgb, u16* __restrict__ wmb) {
  int i = blockIdx.x * 256 + threadIdx.x;
  if (i < CH * INTER2) {
    wtb[i] = f2bf(wt[i]);
    wpb[i] = f2bf(wp[i]);
    wgb[i] = f2bf(wg[i]);
    wmb[i] = f2bf(wm[i]);
  }
}

// ---------------- K1: fused conv GEMM ----------------
// grid (144 p-tiles of 64, NB, 2). z=0: theta(x1)->Tt; z=1: phi,g(x2)->Pt,Gn.
// d-order: d = h*64 + i  (h = p>=NN). Tt/Pt: [n][d] rows 256B. Gn: [d][m].
__global__ __launch_bounds__(256) void k_conv(const float* __restrict__ x1,
                                              const float* __restrict__ x2,
                                              const u16* __restrict__ wtb,
                                              const u16* __restrict__ wpb,
                                              const u16* __restrict__ wgb,
                                              u16* __restrict__ Tt,
                                              u16* __restrict__ Pt,
                                              u16* __restrict__ Gn) {
  __shared__ u16 xT[64 * PCH];  // [p][c] bf16
  __shared__ u16 ot[64 * 72];   // [p][i] out-tile
  const int tid = threadIdx.x;
  const int w = tid >> 6, l = tid & 63, lr = l & 15, lg = l >> 4;
  const int pt = blockIdx.x, b = blockIdx.y, z = blockIdx.z;
  const int p0 = pt * 64;
  const int h = (p0 >= NN) ? 1 : 0;
  const int n0 = p0 - h * NN;
  const float* X = (z ? x2 : x1) + (size_t)b * CH * HW2;

  // stage xT[p][c]
  {
    const int pq = (l & 15) * 4;
    const int cs = w + 4 * (l >> 4);
#pragma unroll
    for (int it = 0; it < 8; it++) {
      const int c = it * 16 + cs;
      float4 v = *(const float4*)(X + (size_t)c * HW2 + p0 + pq);
      xT[(pq + 0) * PCH + c] = f2bf(v.x);
      xT[(pq + 1) * PCH + c] = f2bf(v.y);
      xT[(pq + 2) * PCH + c] = f2bf(v.z);
      xT[(pq + 3) * PCH + c] = f2bf(v.w);
    }
  }
  // weight fragments (shared A/B format): rows w*16+lr
  short8 wsP[4], wsG[4];
  {
    const u16* W1 = z ? wpb : wtb;
#pragma unroll
    for (int ks = 0; ks < 4; ks++)
      wsP[ks] = *(const short8*)(W1 + (w * 16 + lr) * CH + ks * 32 + lg * 8);
    if (z) {
#pragma unroll
      for (int ks = 0; ks < 4; ks++)
        wsG[ks] = *(const short8*)(wgb + (w * 16 + lr) * CH + ks * 32 + lg * 8);
    }
  }
  __syncthreads();
  // x fragments [tp][ks]
  short8 xf[4][4];
#pragma unroll
  for (int tp = 0; tp < 4; tp++)
#pragma unroll
    for (int ks = 0; ks < 4; ks++)
      xf[tp][ks] = *(const short8*)(&xT[(tp * 16 + lr) * PCH + ks * 32 + lg * 8]);

  // P/T part: D[p][i], A=xf (rows p), B=wsP (cols i = w*16+lr)
  f32x4 accP[4];
#pragma unroll
  for (int tp = 0; tp < 4; tp++) {
#pragma unroll
    for (int j = 0; j < 4; j++) accP[tp][j] = 0.f;
#pragma unroll
    for (int ks = 0; ks < 4; ks++)
      accP[tp] = __builtin_amdgcn_mfma_f32_16x16x32_bf16(xf[tp][ks], wsP[ks], accP[tp], 0, 0, 0);
  }
  // write ot[p][i]
#pragma unroll
  for (int tp = 0; tp < 4; tp++) {
#pragma unroll
    for (int j = 0; j < 4; j++)
      ot[(tp * 16 + lg * 4 + j) * 72 + w * 16 + lr] = f2bf(accP[tp][j]);
  }
  // G part: D[i][p], A=wsG (rows i), B=xf (cols p), direct store Gn[d][m]
  if (z) {
    f32x4 accG[4];
#pragma unroll
    for (int tp = 0; tp < 4; tp++) {
#pragma unroll
      for (int j = 0; j < 4; j++) accG[tp][j] = 0.f;
#pragma unroll
      for (int ks = 0; ks < 4; ks++)
        accG[tp] = __builtin_amdgcn_mfma_f32_16x16x32_bf16(wsG[ks], xf[tp][ks], accG[tp], 0, 0, 0);
    }
    u16* Gb = Gn + (size_t)b * CH * NN;
#pragma unroll
    for (int tp = 0; tp < 4; tp++) {
#pragma unroll
      for (int j = 0; j < 4; j++) {
        const int ig = w * 16 + lg * 4 + j;
        Gb[(size_t)((h << 6) + ig) * NN + n0 + tp * 16 + lr] = f2bf(accG[tp][j]);
      }
    }
  }
  __syncthreads();
  // cooperative store of Tt/Pt rows: [n0+p][h*64 .. h*64+63]
  {
    u16* dst = (z ? Pt : Tt) + (size_t)b * NN * CH;
#pragma unroll
    for (int q = 0; q < 2; q++) {
      const int idx = tid * 2 + q;
      const int p = idx >> 3, c8 = (idx & 7) * 8;
      uint4 v = *(const uint4*)(&ot[p * 72 + c8]);
      *(uint4*)(dst + (size_t)(n0 + p) * CH + h * 64 + c8) = v;
    }
  }
}

// ---------------- K2: scores -> E[n][m] via LDS tile (full-line stores), denp partials ----------------
// grid (72*8, eslots): x = mt*8 + s (s -> XCD). Block tile: 64m x 576n, 4 waves (2m x 2n).
__global__ __launch_bounds__(256) void k_scores(const u16* __restrict__ Tt,
                                                const u16* __restrict__ Pt,
                                                u16* __restrict__ E,
                                                float* __restrict__ denp,
                                                int b0) {
  __shared__ u16 Et[64 * 72];  // [n_local][m_local] pitch 72
  const int tid = threadIdx.x;
  const int w = tid >> 6, l = tid & 63, lm = l & 31, lh = l >> 5;
  const int wm2 = w >> 1, wn2 = w & 1;
  const int s = blockIdx.x & 7, mt = blockIdx.x >> 3;
  const int eb = blockIdx.y, b = b0 + eb;
  const int m0 = mt * 64;
  const int nbase = s * SLW;
  const u16* PtB = Pt + (size_t)b * NN * CH;
  const u16* TtB = Tt + (size_t)b * NN * CH;
  u16* Eb = E + (size_t)eb * NN * NN;

  short8 bf[8];
#pragma unroll
  for (int ks = 0; ks < 8; ks++)
    bf[ks] = *(const short8*)(PtB + (size_t)(m0 + wm2 * 32 + lm) * CH + ks * 16 + lh * 8);

  float den_l = 0.f;
  short8 ac[8], an[8];
#pragma unroll
  for (int ks = 0; ks < 8; ks++)
    ac[ks] = *(const short8*)(TtB + (size_t)(nbase + wn2 * 32 + lm) * CH + ks * 16 + lh * 8);

  for (int it = 0; it < 9; it++) {
    if (it + 1 < 9) {
      const int nr = nbase + (it + 1) * 64 + wn2 * 32 + lm;
#pragma unroll
      for (int ks = 0; ks < 8; ks++)
        an[ks] = *(const short8*)(TtB + (size_t)nr * CH + ks * 16 + lh * 8);
    }
    f32x16 acc;
#pragma unroll
    for (int q = 0; q < 16; q++) acc[q] = 0.f;
#pragma unroll
    for (int ks = 0; ks < 8; ks++)
      acc = __builtin_amdgcn_mfma_f32_32x32x16_bf16(ac[ks], bf[ks], acc, 0, 0, 0);
    // epilogue -> LDS
#pragma unroll
    for (int q = 0; q < 16; q += 2) {
      const int nl = wn2 * 32 + (q & 3) + 8 * (q >> 2) + 4 * lh;
      float e0 = exp2f(__builtin_fmaf(acc[q], 1.44269504f, -57.70780163f));
      float e1 = exp2f(__builtin_fmaf(acc[q + 1], 1.44269504f, -57.70780163f));
      den_l += e0;
      den_l += e1;
      u32 pk = cvtpk(e0, e1);
      Et[nl * 72 + wm2 * 32 + lm] = (u16)pk;
      Et[(nl + 1) * 72 + wm2 * 32 + lm] = (u16)(pk >> 16);
    }
    __syncthreads();
    // cooperative full-line store: 64 rows x 128 B
    {
      const int row0 = tid >> 3, col = (tid & 7) * 8;
      const int ng = nbase + it * 64;
#pragma unroll
      for (int p = 0; p < 2; p++) {
        const int r2 = p * 32 + row0;
        uint4 v = *(const uint4*)(&Et[r2 * 72 + col]);
        *(uint4*)(Eb + (size_t)(ng + r2) * NN + m0 + col) = v;
      }
    }
    __syncthreads();
    if (it + 1 < 9) {
#pragma unroll
      for (int ks = 0; ks < 8; ks++) ac[ks] = an[ks];
    }
  }
  den_l += __shfl_xor(den_l, 32, 64);
  __shared__ float dl[4][32];
  if (l < 32) dl[w][l] = den_l;
  __syncthreads();
  if (tid < 64)
    denp[(size_t)(s * NB + b) * NN + m0 + tid] =
        dl[(tid >> 5) * 2][tid & 31] + dl[(tid >> 5) * 2 + 1][tid & 31];
}

// ---------------- K2b: Gd[d][m] = Gn[d][m] / den[m] (coalesced) ----------------
// grid (288, eslots)
__global__ __launch_bounds__(256) void k_gd(const u16* __restrict__ Gn,
                                            const float* __restrict__ denp,
                                            u16* __restrict__ Gd,
                                            int b0) {
  const int q = blockIdx.x * 256 + threadIdx.x;  // 0..73727
  const int d = q / 576, mc = q % 576;
  const int m0 = mc * 8;
  const int b = b0 + blockIdx.y;
  float dn[8];
#pragma unroll
  for (int i = 0; i < 8; i++) dn[i] = 0.f;
#pragma unroll
  for (int s = 0; s < NSLICE; s++) {
    const float* dp = denp + (size_t)(s * NB + b) * NN + m0;
    float4 a = *(const float4*)dp;
    float4 c = *(const float4*)(dp + 4);
    dn[0] += a.x; dn[1] += a.y; dn[2] += a.z; dn[3] += a.w;
    dn[4] += c.x; dn[5] += c.y; dn[6] += c.z; dn[7] += c.w;
  }
  const size_t off = (size_t)b * CH * NN + (size_t)d * NN + m0;
  uint4 v = *(const uint4*)(Gn + off);
  u32 arr[4] = {v.x, v.y, v.z, v.w};
  uint4 o;
  u32 ov[4];
#pragma unroll
  for (int j = 0; j < 4; j++) {
    float lo = bf2f((u16)(arr[j] & 0xffffu)) / dn[2 * j];
    float hi = bf2f((u16)(arr[j] >> 16)) / dn[2 * j + 1];
    ov[j] = cvtpk(lo, hi);
  }
  o.x = ov[0]; o.y = ov[1]; o.z = ov[2]; o.w = ov[3];
  *(uint4*)(Gd + off) = o;
}

// ---------------- K3: Yp[slab] = Gd @ E^T (m97-style LDS GEMM, K-split x SK) ----------------
__global__ __launch_bounds__(256) void k_pv(const u16* __restrict__ E,
                                            const u16* __restrict__ Gd,
                                            float* __restrict__ Yp,
                                            int b0) {
  __shared__ u16 lA[128 * 64];
  __shared__ u16 lB[128 * 64];
  const int tid = threadIdx.x;
  const int w = tid >> 6, l = tid & 63, lr = l & 15, lg = l >> 4;
  const int sk = blockIdx.x / 36, nt = blockIdx.x % 36;
  const int eb = blockIdx.y, b = b0 + eb;
  const int n0 = nt * 128;
  const int k0 = sk * (NN / SK);
  const u16* Eb = E + (size_t)eb * NN * NN;
  const u16* Gb = Gd + (size_t)b * CH * NN;
  const int wm = w >> 1, wn2 = w & 1;
  const int rl = l >> 3;
  const int cg = (l & 7) ^ rl;

  f32x4 acc[4][4];
#pragma unroll
  for (int fa = 0; fa < 4; fa++)
#pragma unroll
    for (int fb = 0; fb < 4; fb++)
#pragma unroll
      for (int j = 0; j < 4; j++) acc[fa][fb][j] = 0.f;

#define STAGE(kk)                                                                   \
  {                                                                                 \
    _Pragma("unroll") for (int r = 0; r < 4; r++) {                                 \
      const int rowA = r * 32 + w * 8 + rl;                                         \
      gl_lds16(Gb + (size_t)rowA * NN + (kk) + cg * 8, &lA[(r * 32 + w * 8) * 64]); \
      gl_lds16(Eb + (size_t)(n0 + rowA) * NN + (kk) + cg * 8,                       \
               &lB[(r * 32 + w * 8) * 64]);                                         \
    }                                                                               \
  }

  STAGE(k0);
  const int NKS = (NN / SK) / 64;  // 9
  for (int st = 0; st < NKS; st++) {
    __syncthreads();
#pragma unroll
    for (int ks2 = 0; ks2 < 2; ks2++) {
      const int cw = ((ks2 * 4 + lg) ^ (lr & 7)) * 8;
      short8 af[4], bfr[4];
#pragma unroll
      for (int fa = 0; fa < 4; fa++)
        af[fa] = *(const short8*)(&lA[(wm * 64 + fa * 16 + lr) * 64 + cw]);
#pragma unroll
      for (int fb = 0; fb < 4; fb++)
        bfr[fb] = *(const short8*)(&lB[(wn2 * 64 + fb * 16 + lr) * 64 + cw]);
#pragma unroll
      for (int fa = 0; fa < 4; fa++)
#pragma unroll
        for (int fb = 0; fb < 4; fb++)
          acc[fa][fb] = __builtin_amdgcn_mfma_f32_16x16x32_bf16(af[fa], bfr[fb], acc[fa][fb], 0, 0, 0);
    }
    __syncthreads();
    if (st + 1 < NKS) STAGE(k0 + (st + 1) * 64);
  }
#undef STAGE
  const int slab = sk * 2 + eb;
  float* Yb = Yp + (size_t)slab * CH * NN;
#pragma unroll
  for (int fa = 0; fa < 4; fa++) {
#pragma unroll
    for (int fb = 0; fb < 4; fb++) {
      const int n = n0 + wn2 * 64 + fb * 16 + lr;
#pragma unroll
      for (int j = 0; j < 4; j++) {
        const int cc = wm * 64 + fa * 16 + lg * 4 + j;
        Yb[(size_t)cc * NN + n] = acc[fa][fb][j];
      }
    }
  }
}

// ---------------- K4: reduce Yp over SK, mask-GEMM + residual ----------------
__global__ __launch_bounds__(256) void k_out(const float* __restrict__ Yp,
                                             const u16* __restrict__ wmb,
                                             const float* __restrict__ x1,
                                             float* __restrict__ out,
                                             int b0) {
  __shared__ u16 yy[64][72];
  const int tid = threadIdx.x;
  const int w = tid >> 6, l = tid & 63, lr = l & 15, lg = l >> 4;
  const int eb = blockIdx.y, b = b0 + eb;
  const int n0 = blockIdx.x * 32;
  const int nl = tid & 31, cch = tid >> 5;

  float v[16];
#pragma unroll
  for (int q = 0; q < 16; q++) v[q] = 0.f;
  for (int s2 = 0; s2 < SK; s2++) {
    const float* base = Yp + ((size_t)(s2 * 2 + eb) * CH + cch * 16) * NN + n0 + nl;
#pragma unroll
    for (int q = 0; q < 16; q++) v[q] += base[(size_t)q * NN];
  }
#pragma unroll
  for (int q = 0; q < 16; q++) {
    const int d = cch * 16 + q;  // d = h*64 + i
    yy[(d >> 6) * 32 + nl][d & 63] = f2bf(v[q]);
  }
  __syncthreads();

  const int wm3 = w >> 1, wp3 = w & 1;
  f32x4 eacc[4][2];
#pragma unroll
  for (int fa = 0; fa < 4; fa++)
#pragma unroll
    for (int fb = 0; fb < 2; fb++)
#pragma unroll
      for (int j = 0; j < 4; j++) eacc[fa][fb][j] = 0.f;
#pragma unroll
  for (int ks = 0; ks < 2; ks++) {
    short8 wa[4];
#pragma unroll
    for (int fa = 0; fa < 4; fa++)
      wa[fa] = *(const short8*)(wmb + (wm3 * 64 + fa * 16 + lr) * 64 + ks * 32 + lg * 8);
    short8 yb[2];
#pragma unroll
    for (int fb = 0; fb < 2; fb++)
      yb[fb] = *(const short8*)(&yy[wp3 * 32 + fb * 16 + lr][ks * 32 + lg * 8]);
#pragma unroll
    for (int fa = 0; fa < 4; fa++)
#pragma unroll
      for (int fb = 0; fb < 2; fb++)
        eacc[fa][fb] = __builtin_amdgcn_mfma_f32_16x16x32_bf16(wa[fa], yb[fb], eacc[fa][fb], 0, 0, 0);
  }
  const float* x1b = x1 + (size_t)b * CH * HW2;
  float* ob = out + (size_t)b * CH * HW2;
#pragma unroll
  for (int fa = 0; fa < 4; fa++) {
#pragma unroll
    for (int fb = 0; fb < 2; fb++) {
      const int pl = wp3 * 32 + fb * 16 + lr;
      const int col = n0 + (pl & 31) + (pl >> 5) * NN;
#pragma unroll
      for (int j = 0; j < 4; j++) {
        const int c = wm3 * 64 + fa * 16 + lg * 4 + j;
        const size_t o = (size_t)c * HW2 + col;
        ob[o] = eacc[fa][fb][j] + x1b[o];
      }
    }
  }
}

extern "C" void kernel_launch(void* const* d_in, const int* in_sizes, int n_in,
                              void* d_out, int out_size, void* d_ws, size_t ws_size,
                              hipStream_t stream) {
  const float* x1 = (const float*)d_in[0];
  const float* x2 = (const float*)d_in[1];
  const float* wt = (const float*)d_in[2];
  const float* wp = (const float*)d_in[3];
  const float* wg = (const float*)d_in[4];
  const float* wm = (const float*)d_in[5];
  float* out = (float*)d_out;

  char* ws = (char*)d_ws;
  const size_t SZ_T = (size_t)NB * NN * CH * 2;
  u16* Tt = (u16*)ws; ws += SZ_T;
  u16* Pt = (u16*)ws; ws += SZ_T;
  u16* Gn = (u16*)ws; ws += SZ_T;
  u16* Gd = (u16*)ws; ws += SZ_T;
  float* denp = (float*)ws; ws += (size_t)NSLICE * NB * NN * 4;
  u16* wtb = (u16*)ws; ws += (size_t)CH * INTER2 * 2;
  u16* wpb = (u16*)ws; ws += (size_t)CH * INTER2 * 2;
  u16* wgb = (u16*)ws; ws += (size_t)CH * INTER2 * 2;
  u16* wmb = (u16*)ws; ws += (size_t)CH * INTER2 * 2;
  float* Yp = (float*)ws; ws += (size_t)16 * CH * NN * 4;
  u16* E = (u16*)ws;

  const size_t fixed = (size_t)(ws - (char*)d_ws);
  const size_t eslab = (size_t)NN * NN * 2;
  int eslots = 0;
  if (ws_size >= fixed + 2 * eslab) eslots = 2;
  else if (ws_size >= fixed + 1 * eslab) eslots = 1;
  if (eslots == 0) return;

  hipLaunchKernelGGL(k_wcvt, dim3(32), dim3(256), 0, stream, wt, wp, wg, wm, wtb, wpb, wgb, wmb);
  hipLaunchKernelGGL(k_conv, dim3(144, NB, 2), dim3(256), 0, stream, x1, x2, wtb, wpb, wgb, Tt, Pt, Gn);
  for (int b0 = 0; b0 < NB; b0 += eslots) {
    hipLaunchKernelGGL(k_scores, dim3(72 * 8, eslots), dim3(256), 0, stream, Tt, Pt, E, denp, b0);
    hipLaunchKernelGGL(k_gd, dim3(288, eslots), dim3(256), 0, stream, Gn, denp, Gd, b0);
    hipLaunchKernelGGL(k_pv, dim3(SK * 36, eslots), dim3(256), 0, stream, E, Gd, Yp, b0);
    hipLaunchKernelGGL(k_out, dim3(144, eslots), dim3(256), 0, stream, Yp, wmb, x1, out, b0);
  }
}